// Round 7
// baseline (652.501 us; speedup 1.0000x reference)
//
#include <hip/hip_runtime.h>

#define N_NODES 100000
#define N_EDGES 800000
#define HID 64
#define NGRAPH 64
#define OUTC 2
#define BN_EPS 1e-5f
#define NSCAN_BLK ((N_NODES + 255) / 256)   // 391
#define GEMM_BLK ((N_NODES + 63) / 64)      // 1563
#define POOL_SUB 16

typedef __attribute__((ext_vector_type(8))) short bf16x8;
typedef __attribute__((ext_vector_type(4))) float f32x4;

__device__ __forceinline__ unsigned short f2bf(float f) {
    unsigned int u = __float_as_uint(f);
    u = (u + 0x7FFFu + ((u >> 16) & 1u)) >> 16;   // round-to-nearest-even
    return (unsigned short)u;
}
__device__ __forceinline__ float bflo(unsigned int u) { return __uint_as_float(u << 16); }
__device__ __forceinline__ float bfhi(unsigned int u) { return __uint_as_float(u & 0xFFFF0000u); }
__device__ __forceinline__ unsigned int bfpack(float a, float b) {
    return (unsigned int)f2bf(a) | ((unsigned int)f2bf(b) << 16);
}

// ---------------------------------------------------------------------------
// GEMM via bf16 MFMA: Y[n,64](bf16) = T(X)[n,64] @ W[64,64] (+bias, opt dinv)
// X is fp32 (IN_FP32) or bf16. T = optional BN scale/shift (+ReLU), fp32.
// MFMA 16x16x32 bf16, fp32 accumulate. A/B staged with identical k-layout;
// C/D layout col=lane&15, row=(lane>>4)*4+reg (HW-verified).
// STATS: per-block column sum/sumsq partials (fp32, pre-rounding).
// ---------------------------------------------------------------------------
template <int IN_MODE, bool IN_FP32, bool ADD_BIAS, bool ROW_SCALE, bool STATS>
__global__ __launch_bounds__(256) void k_gemm(const void* __restrict__ Xv,
                                              const float* __restrict__ W,
                                              const float* __restrict__ bias,
                                              const float* __restrict__ dinv,
                                              const float* __restrict__ scsh,
                                              unsigned short* __restrict__ Y,
                                              float* __restrict__ partial, int n) {
    __shared__ __align__(16) unsigned short sXb[64][72];  // bf16 X tile (pad 72)
    __shared__ __align__(16) unsigned short sWT[64][72];  // bf16 W^T: sWT[c][k]
    __shared__ float sDinv[64];
    const int tid  = threadIdx.x;
    const int row0 = blockIdx.x * 64;

    // stage W^T (bf16): sWT[c][k] = W[k][c]
    #pragma unroll
    for (int i = tid; i < 1024; i += 256) {
        int k = i >> 4, c4 = (i & 15) << 2;
        float4 w = *reinterpret_cast<const float4*>(&W[k * 64 + c4]);
        sWT[c4 + 0][k] = f2bf(w.x);
        sWT[c4 + 1][k] = f2bf(w.y);
        sWT[c4 + 2][k] = f2bf(w.z);
        sWT[c4 + 3][k] = f2bf(w.w);
    }
    // stage X tile (64x64) with fused fp32 BN/ReLU transform -> bf16
    if (IN_FP32) {
        const float* X = (const float*)Xv;
        #pragma unroll
        for (int f = tid; f < 1024; f += 256) {
            int r = f >> 4, c4 = (f & 15) << 2;
            float4 v = make_float4(0.f, 0.f, 0.f, 0.f);
            if (row0 + r < n)
                v = *reinterpret_cast<const float4*>(&X[(size_t)(row0 + r) * HID + c4]);
            if (IN_MODE >= 1) {
                float4 sc = *reinterpret_cast<const float4*>(&scsh[c4]);
                float4 sh = *reinterpret_cast<const float4*>(&scsh[64 + c4]);
                v.x = v.x * sc.x + sh.x; v.y = v.y * sc.y + sh.y;
                v.z = v.z * sc.z + sh.z; v.w = v.w * sc.w + sh.w;
                if (IN_MODE == 2) {
                    v.x = fmaxf(v.x, 0.f); v.y = fmaxf(v.y, 0.f);
                    v.z = fmaxf(v.z, 0.f); v.w = fmaxf(v.w, 0.f);
                }
            }
            sXb[r][c4 + 0] = f2bf(v.x);
            sXb[r][c4 + 1] = f2bf(v.y);
            sXb[r][c4 + 2] = f2bf(v.z);
            sXb[r][c4 + 3] = f2bf(v.w);
        }
    } else {
        const unsigned short* X = (const unsigned short*)Xv;
        #pragma unroll
        for (int f = tid; f < 512; f += 256) {
            int r = f >> 3, c8 = (f & 7) << 3;
            uint4 u = make_uint4(0u, 0u, 0u, 0u);
            if (row0 + r < n)
                u = *reinterpret_cast<const uint4*>(&X[(size_t)(row0 + r) * HID + c8]);
            if (IN_MODE >= 1) {
                float v[8];
                v[0] = bflo(u.x); v[1] = bfhi(u.x);
                v[2] = bflo(u.y); v[3] = bfhi(u.y);
                v[4] = bflo(u.z); v[5] = bfhi(u.z);
                v[6] = bflo(u.w); v[7] = bfhi(u.w);
                #pragma unroll
                for (int k = 0; k < 8; ++k) {
                    v[k] = v[k] * scsh[c8 + k] + scsh[64 + c8 + k];
                    if (IN_MODE == 2) v[k] = fmaxf(v[k], 0.f);
                }
                u.x = bfpack(v[0], v[1]); u.y = bfpack(v[2], v[3]);
                u.z = bfpack(v[4], v[5]); u.w = bfpack(v[6], v[7]);
            }
            *reinterpret_cast<uint4*>(&sXb[r][c8]) = u;
        }
    }
    if (ROW_SCALE && tid < 64)
        sDinv[tid] = (row0 + tid < n) ? dinv[row0 + tid] : 0.f;
    __syncthreads();

    const int lane = tid & 63;
    const int wv   = tid >> 6;          // wave id -> col tile wv*16..+15
    const int cl   = lane & 15;         // col within tile
    const int kg   = lane >> 4;         // k-group 0..3
    const int col  = (wv << 4) + cl;    // column in 64-wide tile

    const f32x4 zero = {0.f, 0.f, 0.f, 0.f};
    f32x4 acc[4];
    #pragma unroll
    for (int m = 0; m < 4; ++m) acc[m] = zero;

    #pragma unroll
    for (int k0 = 0; k0 < 64; k0 += 32) {
        bf16x8 bfrag = *reinterpret_cast<const bf16x8*>(&sWT[col][k0 + (kg << 3)]);
        #pragma unroll
        for (int m = 0; m < 4; ++m) {
            bf16x8 afrag = *reinterpret_cast<const bf16x8*>(&sXb[(m << 4) + cl][k0 + (kg << 3)]);
            acc[m] = __builtin_amdgcn_mfma_f32_16x16x32_bf16(afrag, bfrag, acc[m], 0, 0, 0);
        }
    }

    const float bb = ADD_BIAS ? bias[col] : 0.f;
    float colS = 0.f, colQ = 0.f;
    #pragma unroll
    for (int m = 0; m < 4; ++m) {
        #pragma unroll
        for (int j = 0; j < 4; ++j) {
            int rl = (m << 4) + (kg << 2) + j;   // C/D: row=(lane>>4)*4+reg
            int r  = row0 + rl;
            if (r < n) {
                float s = ROW_SCALE ? sDinv[rl] : 1.f;
                float o = acc[m][j] * s + bb;
                Y[(size_t)r * HID + col] = f2bf(o);
                if (STATS) { colS += o; colQ += o * o; }
            }
        }
    }
    if (STATS) {
        colS += __shfl_xor(colS, 16); colQ += __shfl_xor(colQ, 16);
        colS += __shfl_xor(colS, 32); colQ += __shfl_xor(colQ, 32);
        if (kg == 0) {
            partial[blockIdx.x * 128 + col]      = colS;
            partial[blockIdx.x * 128 + 64 + col] = colQ;
        }
    }
}

// Reduce per-block partials -> scale/shift. One block per column.
__global__ __launch_bounds__(256) void k_statsfin(const float* __restrict__ partial,
                                                  const float* __restrict__ g,
                                                  const float* __restrict__ beta,
                                                  float* __restrict__ scsh, int n) {
    int c = blockIdx.x, t = threadIdx.x;
    float S = 0.f, Q = 0.f;
    for (int b = t; b < GEMM_BLK; b += 256) {
        S += partial[b * 128 + c];
        Q += partial[b * 128 + 64 + c];
    }
    __shared__ float ss[256], sq[256];
    ss[t] = S; sq[t] = Q;
    __syncthreads();
    for (int off = 128; off > 0; off >>= 1) {
        if (t < off) { ss[t] += ss[t + off]; sq[t] += sq[t + off]; }
        __syncthreads();
    }
    if (t == 0) {
        float nf = (float)n;
        float m  = ss[0] / nf;
        float v  = sq[0] / nf - m * m;
        float sc = rsqrtf(v + BN_EPS) * g[c];
        scsh[c]      = sc;
        scsh[64 + c] = beta[c] - m * sc;
    }
}

// ---------------------------------------------------------------------------
// CSR build
// ---------------------------------------------------------------------------
__global__ __launch_bounds__(256) void k_deg(const int* __restrict__ dst,
                                             int* __restrict__ indeg) {
    int e = blockIdx.x * 256 + threadIdx.x;
    if (e < N_EDGES) atomicAdd(&indeg[dst[e]], 1);
}

__global__ __launch_bounds__(256) void k_scanpart(const int* __restrict__ indeg,
                                                  int* __restrict__ bsum) {
    __shared__ int s[256];
    int i = blockIdx.x * 256 + threadIdx.x;
    s[threadIdx.x] = (i < N_NODES) ? indeg[i] : 0;
    __syncthreads();
    for (int off = 128; off > 0; off >>= 1) {
        if (threadIdx.x < off) s[threadIdx.x] += s[threadIdx.x + off];
        __syncthreads();
    }
    if (threadIdx.x == 0) bsum[blockIdx.x] = s[0];
}

__global__ __launch_bounds__(512) void k_scanmid(int* __restrict__ bsum, int nblk) {
    __shared__ int s[512];
    int t = threadIdx.x;
    int v = (t < nblk) ? bsum[t] : 0;
    s[t] = v;
    __syncthreads();
    for (int off = 1; off < 512; off <<= 1) {
        int x = (t >= off) ? s[t - off] : 0;
        __syncthreads();
        s[t] += x;
        __syncthreads();
    }
    if (t < nblk) bsum[t] = s[t] - v;   // exclusive
}

// scanfinal + dinv fused (both node-wise over indeg)
__global__ __launch_bounds__(256) void k_scanfinal(const int* __restrict__ indeg,
                                                   const int* __restrict__ bsum,
                                                   int* __restrict__ rowptr,
                                                   float* __restrict__ dinv) {
    __shared__ int s[256];
    int t = threadIdx.x;
    int i = blockIdx.x * 256 + t;
    int v = (i < N_NODES) ? indeg[i] : 0;
    s[t] = v;
    __syncthreads();
    for (int off = 1; off < 256; off <<= 1) {
        int x = (t >= off) ? s[t - off] : 0;
        __syncthreads();
        s[t] += x;
        __syncthreads();
    }
    if (i < N_NODES) {
        rowptr[i] = bsum[blockIdx.x] + s[t] - v;
        dinv[i]   = rsqrtf((float)v + 1.f);
    }
    if (i == 0) rowptr[N_NODES] = N_EDGES;
}

__global__ __launch_bounds__(256) void k_fill(const int* __restrict__ src,
                                              const int* __restrict__ dst,
                                              const int* __restrict__ rowptr,
                                              int* __restrict__ indeg,
                                              int* __restrict__ colidx) {
    int e = blockIdx.x * 256 + threadIdx.x;
    if (e >= N_EDGES) return;
    int d = dst[e];
    int pos = rowptr[d] + (atomicSub(&indeg[d], 1) - 1);
    colidx[pos] = src[e];
}

// ---------------------------------------------------------------------------
// Fused gather + conv finalize: one wave per dst node, 8 edge-slots x 8
// col-lanes x bf16x8 (16B/lane). HW, Hin, Out all bf16; accumulation fp32.
// ---------------------------------------------------------------------------
template <int IN_MODE, bool RELU>
__global__ __launch_bounds__(256) void k_gather(const int* __restrict__ rowptr,
                                                const int* __restrict__ colidx,
                                                const unsigned short* __restrict__ HWb,
                                                const unsigned short* __restrict__ Hin,
                                                const float* __restrict__ dinv,
                                                const float* __restrict__ bias,
                                                const float* __restrict__ scsh,
                                                unsigned short* __restrict__ Out) {
    int d = blockIdx.x * 4 + (threadIdx.x >> 6);
    if (d >= N_NODES) return;
    const int lane = threadIdx.x & 63;
    const int slot = lane >> 3;          // 0..7 edge slot
    const int c8   = (lane & 7) << 3;    // column base (8 cols per lane)
    const int j0 = rowptr[d], j1 = rowptr[d + 1];

    float acc[8];
    #pragma unroll
    for (int k = 0; k < 8; ++k) acc[k] = 0.f;

    if (slot == 7) {  // self-loop term
        uint4 v = *reinterpret_cast<const uint4*>(&HWb[(size_t)d * HID + c8]);
        acc[0] += bflo(v.x); acc[1] += bfhi(v.x);
        acc[2] += bflo(v.y); acc[3] += bfhi(v.y);
        acc[4] += bflo(v.z); acc[5] += bfhi(v.z);
        acc[6] += bflo(v.w); acc[7] += bfhi(v.w);
    }
    for (int j = j0 + slot; j < j1; j += 8) {
        int s = colidx[j];
        uint4 v = *reinterpret_cast<const uint4*>(&HWb[(size_t)s * HID + c8]);
        acc[0] += bflo(v.x); acc[1] += bfhi(v.x);
        acc[2] += bflo(v.y); acc[3] += bfhi(v.y);
        acc[4] += bflo(v.z); acc[5] += bfhi(v.z);
        acc[6] += bflo(v.w); acc[7] += bfhi(v.w);
    }
    // reduce across the 8 slots (lane bits 3,4,5)
    #pragma unroll
    for (int m = 8; m < 64; m <<= 1) {
        #pragma unroll
        for (int k = 0; k < 8; ++k) acc[k] += __shfl_xor(acc[k], m);
    }

    if (slot == 0) {
        uint4 hv = *reinterpret_cast<const uint4*>(&Hin[(size_t)d * HID + c8]);
        float h[8];
        h[0] = bflo(hv.x); h[1] = bfhi(hv.x);
        h[2] = bflo(hv.y); h[3] = bfhi(hv.y);
        h[4] = bflo(hv.z); h[5] = bfhi(hv.z);
        h[6] = bflo(hv.w); h[7] = bfhi(hv.w);
        if (IN_MODE == 1) {
            #pragma unroll
            for (int k = 0; k < 8; ++k)
                h[k] = h[k] * scsh[c8 + k] + scsh[64 + c8 + k];
        }
        float di = dinv[d];
        float o[8];
        #pragma unroll
        for (int k = 0; k < 8; ++k) {
            o[k] = acc[k] * di + bias[c8 + k] + h[k];
            if (RELU) o[k] = fmaxf(o[k], 0.f);
        }
        uint4 ov;
        ov.x = bfpack(o[0], o[1]); ov.y = bfpack(o[2], o[3]);
        ov.z = bfpack(o[4], o[5]); ov.w = bfpack(o[6], o[7]);
        *reinterpret_cast<uint4*>(&Out[(size_t)d * HID + c8]) = ov;
    }
}

// ---------------------------------------------------------------------------
// Two-stage segment-mean pool over sorted batch (stage 2 fused into k_final)
// ---------------------------------------------------------------------------
__device__ __forceinline__ int lowerb(const int* __restrict__ b, int n, int v) {
    int lo = 0, hi = n;
    while (lo < hi) { int m = (lo + hi) >> 1; if (b[m] < v) lo = m + 1; else hi = m; }
    return lo;
}

__global__ __launch_bounds__(256) void k_pool1(const unsigned short* __restrict__ Y,
                                               const int* __restrict__ batch,
                                               float* __restrict__ partial2) {
    int g  = blockIdx.x >> 4;
    int sb = blockIdx.x & 15;
    int tid = threadIdx.x, col = tid & 63, rg = tid >> 6;
    int lo = lowerb(batch, N_NODES, g);
    int hi = lowerb(batch, N_NODES, g + 1);
    int cnt = hi - lo;
    int st = lo + (int)(((long long)cnt * sb) >> 4);
    int en = lo + (int)(((long long)cnt * (sb + 1)) >> 4);
    float s = 0.f;
    for (int r = st + rg; r < en; r += 4)
        s += bflo((unsigned int)Y[(size_t)r * HID + col]);
    __shared__ float ls[4][64];
    ls[rg][col] = s;
    __syncthreads();
    if (tid < 64)
        partial2[(size_t)blockIdx.x * 64 + tid] =
            ls[0][tid] + ls[1][tid] + ls[2][tid] + ls[3][tid];
}

// ---------------------------------------------------------------------------
// Final head (pool stage-2 + final BN fused in)
// ---------------------------------------------------------------------------
__global__ __launch_bounds__(256) void k_final(const float* __restrict__ partial2,
                                               const int* __restrict__ batch,
                                               const float* __restrict__ scsh,
                                               const float* __restrict__ W0,
                                               const float* __restrict__ b0,
                                               const float* __restrict__ W1,
                                               const float* __restrict__ b1,
                                               const float* __restrict__ W2,
                                               const float* __restrict__ b2,
                                               float* __restrict__ out) {
    __shared__ float P[64][65];
    __shared__ float Z[64][65];
    int tid = threadIdx.x;
    for (int i = tid; i < NGRAPH * HID; i += 256) {
        int g = i >> 6, c = i & 63;
        float S = 0.f;
        #pragma unroll
        for (int sb = 0; sb < POOL_SUB; ++sb)
            S += partial2[(size_t)(g * POOL_SUB + sb) * 64 + c];
        int lo = lowerb(batch, N_NODES, g);
        int hi = lowerb(batch, N_NODES, g + 1);
        int cnt = hi - lo;
        float v = 0.f;
        if (cnt > 0) v = (S / (float)cnt) * scsh[c] + scsh[64 + c];
        P[g][c] = v;
    }
    __syncthreads();
    for (int t = 0; t < 16; ++t) {
        int o = tid + 256 * t; int r = o >> 6, c = o & 63;
        float acc = b0[c];
        #pragma unroll 8
        for (int k = 0; k < 64; ++k) acc += P[r][k] * W0[k * 64 + c];
        Z[r][c] = fmaxf(acc, 0.f);
    }
    __syncthreads();
    for (int t = 0; t < 16; ++t) {
        int o = tid + 256 * t; int r = o >> 6, c = o & 63;
        float acc = b1[c];
        #pragma unroll 8
        for (int k = 0; k < 64; ++k) acc += Z[r][k] * W1[k * 64 + c];
        P[r][c] = fmaxf(acc, 0.f);
    }
    __syncthreads();
    if (tid < NGRAPH * OUTC) {
        int r = tid >> 1, c = tid & 1;
        float acc = b2[c];
        #pragma unroll 8
        for (int k = 0; k < 64; ++k) acc += P[r][k] * W2[k * OUTC + c];
        out[tid] = acc;
    }
}

// ---------------------------------------------------------------------------
extern "C" void kernel_launch(void* const* d_in, const int* in_sizes, int n_in,
                              void* d_out, int out_size, void* d_ws, size_t ws_size,
                              hipStream_t stream) {
    const float* x        = (const float*)d_in[0];
    const int*   ei       = (const int*)d_in[1];
    const int*   batch    = (const int*)d_in[2];
    const float* pre_W    = (const float*)d_in[3];
    const float* pre_b    = (const float*)d_in[4];
    const float* pre_g    = (const float*)d_in[5];
    const float* pre_beta = (const float*)d_in[6];
    const float* conv_W   = (const float*)d_in[7];
    const float* conv_b   = (const float*)d_in[8];
    const float* post_W   = (const float*)d_in[9];
    const float* post_b   = (const float*)d_in[10];
    const float* post_g   = (const float*)d_in[11];
    const float* post_beta= (const float*)d_in[12];
    const float* fW0 = (const float*)d_in[13];
    const float* fb0 = (const float*)d_in[14];
    const float* fW1 = (const float*)d_in[15];
    const float* fb1 = (const float*)d_in[16];
    const float* fW2 = (const float*)d_in[17];
    const float* fb2 = (const float*)d_in[18];
    float* out = (float*)d_out;

    const size_t NH = (size_t)N_NODES * HID;
    float* ws       = (float*)d_ws;
    float* A        = ws;              // bf16 trunk buffer (NH ushorts)
    float* B        = A + NH;          // bf16 HW buffer (NH ushorts)
    float* C        = B + NH;          // bf16 trunk buffer (NH ushorts)
    float* dinv     = C + NH;                         // N
    float* partial  = dinv + N_NODES;                 // GEMM_BLK*128
    float* scsh     = partial + (size_t)GEMM_BLK*128; // 6 slots of 128
    float* partial2 = scsh + 6 * 128;                 // 1024*64
    int*   indeg    = (int*)(partial2 + NGRAPH * POOL_SUB * 64);
    int*   rowptr   = indeg + N_NODES;                // N+1
    int*   colidx   = rowptr + N_NODES + 1;           // E
    int*   bsum     = colidx + N_EDGES;               // NSCAN_BLK
    unsigned short* Ab  = (unsigned short*)A;
    unsigned short* Bb  = (unsigned short*)B;
    unsigned short* Cb  = (unsigned short*)C;

    const int* srcp = ei;
    const int* dstp = ei + N_EDGES;

    const int gEdge  = (N_EDGES + 255) / 256;
    const int gNode4 = (N_NODES + 3) / 4;

    // ---- CSR build ----
    hipMemsetAsync(indeg, 0, N_NODES * sizeof(int), stream);
    k_deg<<<gEdge, 256, 0, stream>>>(dstp, indeg);
    k_scanpart<<<NSCAN_BLK, 256, 0, stream>>>(indeg, bsum);
    k_scanmid<<<1, 512, 0, stream>>>(bsum, NSCAN_BLK);
    k_scanfinal<<<NSCAN_BLK, 256, 0, stream>>>(indeg, bsum, rowptr, dinv);
    k_fill<<<gEdge, 256, 0, stream>>>(srcp, dstp, rowptr, indeg, colidx);

    // ---- pre-processing: GEMM(+fused prev BN/ReLU, +stats) ----
    k_gemm<0, true,  true, false, true><<<GEMM_BLK, 256, 0, stream>>>(x, pre_W, pre_b, nullptr, nullptr, Ab, partial, N_NODES);
    k_statsfin<<<64, 256, 0, stream>>>(partial, pre_g, pre_beta, scsh + 0 * 128, N_NODES);

    k_gemm<2, false, true, false, true><<<GEMM_BLK, 256, 0, stream>>>(Ab, pre_W + 4096, pre_b + 64, nullptr, scsh + 0 * 128, Cb, partial, N_NODES);
    k_statsfin<<<64, 256, 0, stream>>>(partial, pre_g + 64, pre_beta + 64, scsh + 1 * 128, N_NODES);

    k_gemm<2, false, true, false, true><<<GEMM_BLK, 256, 0, stream>>>(Cb, pre_W + 2 * 4096, pre_b + 128, nullptr, scsh + 1 * 128, Ab, partial, N_NODES);
    k_statsfin<<<64, 256, 0, stream>>>(partial, pre_g + 128, pre_beta + 128, scsh + 2 * 128, N_NODES);

    // ---- GCNConv stack (all buffers bf16) ----
    for (int i = 0; i < 6; ++i) {
        const unsigned short* in = (i & 1) ? Cb : Ab;
        unsigned short*     outb = (i & 1) ? Ab : Cb;
        const float* Wl = conv_W + i * 4096;
        const float* bl = conv_b + i * 64;
        if (i == 0)
            k_gemm<1, false, false, true, false><<<GEMM_BLK, 256, 0, stream>>>(in, Wl, nullptr, dinv, scsh + 2 * 128, Bb, nullptr, N_NODES);
        else
            k_gemm<0, false, false, true, false><<<GEMM_BLK, 256, 0, stream>>>(in, Wl, nullptr, dinv, nullptr, Bb, nullptr, N_NODES);

        if (i == 0)
            k_gather<1, true ><<<gNode4, 256, 0, stream>>>(rowptr, colidx, Bb, in, dinv, bl, scsh + 2 * 128, outb);
        else if (i != 5)
            k_gather<0, true ><<<gNode4, 256, 0, stream>>>(rowptr, colidx, Bb, in, dinv, bl, nullptr, outb);
        else
            k_gather<0, false><<<gNode4, 256, 0, stream>>>(rowptr, colidx, Bb, in, dinv, bl, nullptr, outb);
    }
    // conv output in Ab (i=5 odd -> outb=Ab)

    // ---- post-processing ----
    k_gemm<0, false, true, false, true><<<GEMM_BLK, 256, 0, stream>>>(Ab, post_W, post_b, nullptr, nullptr, Cb, partial, N_NODES);
    k_statsfin<<<64, 256, 0, stream>>>(partial, post_g, post_beta, scsh + 3 * 128, N_NODES);

    k_gemm<2, false, true, false, true><<<GEMM_BLK, 256, 0, stream>>>(Cb, post_W + 4096, post_b + 64, nullptr, scsh + 3 * 128, Ab, partial, N_NODES);
    k_statsfin<<<64, 256, 0, stream>>>(partial, post_g + 64, post_beta + 64, scsh + 4 * 128, N_NODES);

    k_gemm<2, false, true, false, true><<<GEMM_BLK, 256, 0, stream>>>(Ab, post_W + 2 * 4096, post_b + 128, nullptr, scsh + 4 * 128, Cb, partial, N_NODES);
    k_statsfin<<<64, 256, 0, stream>>>(partial, post_g + 128, post_beta + 128, scsh + 5 * 128, N_NODES);

    // ---- pool stage 1 + fused(pool2 + BN + head) ----
    k_pool1<<<NGRAPH * POOL_SUB, 256, 0, stream>>>(Cb, batch, partial2);
    k_final<<<1, 256, 0, stream>>>(partial2, batch, scsh + 5 * 128,
                                   fW0, fb0, fW1, fb1, fW2, fb2, out);
}

// Round 8
// 573.293 us; speedup vs baseline: 1.1382x; 1.1382x over previous
//
#include <hip/hip_runtime.h>

#define N_NODES 100000
#define N_EDGES 800000
#define HID 64
#define NGRAPH 64
#define OUTC 2
#define BN_EPS 1e-5f
#define NSCAN_BLK ((N_NODES + 255) / 256)   // 391
#define GEMM_BLK ((N_NODES + 63) / 64)      // 1563
#define POOL_SUB 16

typedef __attribute__((ext_vector_type(8))) short bf16x8;
typedef __attribute__((ext_vector_type(4))) float f32x4;

__device__ __forceinline__ unsigned short f2bf(float f) {
    unsigned int u = __float_as_uint(f);
    u = (u + 0x7FFFu + ((u >> 16) & 1u)) >> 16;   // round-to-nearest-even
    return (unsigned short)u;
}
__device__ __forceinline__ float bflo(unsigned int u) { return __uint_as_float(u << 16); }
__device__ __forceinline__ float bfhi(unsigned int u) { return __uint_as_float(u & 0xFFFF0000u); }
__device__ __forceinline__ unsigned int bfpack(float a, float b) {
    return (unsigned int)f2bf(a) | ((unsigned int)f2bf(b) << 16);
}

// ---------------------------------------------------------------------------
// GEMM via bf16 MFMA: Y[n,64](bf16) = T(X)[n,64] @ W[64,64] (+bias, opt dinv)
// X is fp32 (IN_FP32) or bf16. T = optional BN scale/shift (+ReLU), fp32.
// MFMA 16x16x32 bf16, fp32 accumulate. A/B staged with identical k-layout;
// C/D layout col=lane&15, row=(lane>>4)*4+reg (HW-verified).
// STATS: per-block column sum/sumsq partials (fp32, pre-rounding).
// ---------------------------------------------------------------------------
template <int IN_MODE, bool IN_FP32, bool ADD_BIAS, bool ROW_SCALE, bool STATS>
__global__ __launch_bounds__(256) void k_gemm(const void* __restrict__ Xv,
                                              const float* __restrict__ W,
                                              const float* __restrict__ bias,
                                              const float* __restrict__ dinv,
                                              const float* __restrict__ scsh,
                                              unsigned short* __restrict__ Y,
                                              float* __restrict__ partial, int n) {
    __shared__ __align__(16) unsigned short sXb[64][72];  // bf16 X tile (pad 72)
    __shared__ __align__(16) unsigned short sWT[64][72];  // bf16 W^T: sWT[c][k]
    __shared__ float sDinv[64];
    const int tid  = threadIdx.x;
    const int row0 = blockIdx.x * 64;

    // stage W^T (bf16): sWT[c][k] = W[k][c]
    #pragma unroll
    for (int i = tid; i < 1024; i += 256) {
        int k = i >> 4, c4 = (i & 15) << 2;
        float4 w = *reinterpret_cast<const float4*>(&W[k * 64 + c4]);
        sWT[c4 + 0][k] = f2bf(w.x);
        sWT[c4 + 1][k] = f2bf(w.y);
        sWT[c4 + 2][k] = f2bf(w.z);
        sWT[c4 + 3][k] = f2bf(w.w);
    }
    // stage X tile (64x64) with fused fp32 BN/ReLU transform -> bf16
    if (IN_FP32) {
        const float* X = (const float*)Xv;
        #pragma unroll
        for (int f = tid; f < 1024; f += 256) {
            int r = f >> 4, c4 = (f & 15) << 2;
            float4 v = make_float4(0.f, 0.f, 0.f, 0.f);
            if (row0 + r < n)
                v = *reinterpret_cast<const float4*>(&X[(size_t)(row0 + r) * HID + c4]);
            if (IN_MODE >= 1) {
                float4 sc = *reinterpret_cast<const float4*>(&scsh[c4]);
                float4 sh = *reinterpret_cast<const float4*>(&scsh[64 + c4]);
                v.x = v.x * sc.x + sh.x; v.y = v.y * sc.y + sh.y;
                v.z = v.z * sc.z + sh.z; v.w = v.w * sc.w + sh.w;
                if (IN_MODE == 2) {
                    v.x = fmaxf(v.x, 0.f); v.y = fmaxf(v.y, 0.f);
                    v.z = fmaxf(v.z, 0.f); v.w = fmaxf(v.w, 0.f);
                }
            }
            sXb[r][c4 + 0] = f2bf(v.x);
            sXb[r][c4 + 1] = f2bf(v.y);
            sXb[r][c4 + 2] = f2bf(v.z);
            sXb[r][c4 + 3] = f2bf(v.w);
        }
    } else {
        const unsigned short* X = (const unsigned short*)Xv;
        #pragma unroll
        for (int f = tid; f < 512; f += 256) {
            int r = f >> 3, c8 = (f & 7) << 3;
            uint4 u = make_uint4(0u, 0u, 0u, 0u);
            if (row0 + r < n)
                u = *reinterpret_cast<const uint4*>(&X[(size_t)(row0 + r) * HID + c8]);
            if (IN_MODE >= 1) {
                float v[8];
                v[0] = bflo(u.x); v[1] = bfhi(u.x);
                v[2] = bflo(u.y); v[3] = bfhi(u.y);
                v[4] = bflo(u.z); v[5] = bfhi(u.z);
                v[6] = bflo(u.w); v[7] = bfhi(u.w);
                #pragma unroll
                for (int k = 0; k < 8; ++k) {
                    v[k] = v[k] * scsh[c8 + k] + scsh[64 + c8 + k];
                    if (IN_MODE == 2) v[k] = fmaxf(v[k], 0.f);
                }
                u.x = bfpack(v[0], v[1]); u.y = bfpack(v[2], v[3]);
                u.z = bfpack(v[4], v[5]); u.w = bfpack(v[6], v[7]);
            }
            *reinterpret_cast<uint4*>(&sXb[r][c8]) = u;
        }
    }
    if (ROW_SCALE && tid < 64)
        sDinv[tid] = (row0 + tid < n) ? dinv[row0 + tid] : 0.f;
    __syncthreads();

    const int lane = tid & 63;
    const int wv   = tid >> 6;          // wave id -> col tile wv*16..+15
    const int cl   = lane & 15;         // col within tile
    const int kg   = lane >> 4;         // k-group 0..3
    const int col  = (wv << 4) + cl;    // column in 64-wide tile

    const f32x4 zero = {0.f, 0.f, 0.f, 0.f};
    f32x4 acc[4];
    #pragma unroll
    for (int m = 0; m < 4; ++m) acc[m] = zero;

    #pragma unroll
    for (int k0 = 0; k0 < 64; k0 += 32) {
        bf16x8 bfrag = *reinterpret_cast<const bf16x8*>(&sWT[col][k0 + (kg << 3)]);
        #pragma unroll
        for (int m = 0; m < 4; ++m) {
            bf16x8 afrag = *reinterpret_cast<const bf16x8*>(&sXb[(m << 4) + cl][k0 + (kg << 3)]);
            acc[m] = __builtin_amdgcn_mfma_f32_16x16x32_bf16(afrag, bfrag, acc[m], 0, 0, 0);
        }
    }

    const float bb = ADD_BIAS ? bias[col] : 0.f;
    float colS = 0.f, colQ = 0.f;
    #pragma unroll
    for (int m = 0; m < 4; ++m) {
        #pragma unroll
        for (int j = 0; j < 4; ++j) {
            int rl = (m << 4) + (kg << 2) + j;   // C/D: row=(lane>>4)*4+reg
            int r  = row0 + rl;
            if (r < n) {
                float s = ROW_SCALE ? sDinv[rl] : 1.f;
                float o = acc[m][j] * s + bb;
                Y[(size_t)r * HID + col] = f2bf(o);
                if (STATS) { colS += o; colQ += o * o; }
            }
        }
    }
    if (STATS) {
        colS += __shfl_xor(colS, 16); colQ += __shfl_xor(colQ, 16);
        colS += __shfl_xor(colS, 32); colQ += __shfl_xor(colQ, 32);
        if (kg == 0) {
            partial[blockIdx.x * 128 + col]      = colS;
            partial[blockIdx.x * 128 + 64 + col] = colQ;
        }
    }
}

// Reduce per-block partials -> scale/shift. One block per column.
__global__ __launch_bounds__(256) void k_statsfin(const float* __restrict__ partial,
                                                  const float* __restrict__ g,
                                                  const float* __restrict__ beta,
                                                  float* __restrict__ scsh, int n) {
    int c = blockIdx.x, t = threadIdx.x;
    float S = 0.f, Q = 0.f;
    for (int b = t; b < GEMM_BLK; b += 256) {
        S += partial[b * 128 + c];
        Q += partial[b * 128 + 64 + c];
    }
    __shared__ float ss[256], sq[256];
    ss[t] = S; sq[t] = Q;
    __syncthreads();
    for (int off = 128; off > 0; off >>= 1) {
        if (t < off) { ss[t] += ss[t + off]; sq[t] += sq[t + off]; }
        __syncthreads();
    }
    if (t == 0) {
        float nf = (float)n;
        float m  = ss[0] / nf;
        float v  = sq[0] / nf - m * m;
        float sc = rsqrtf(v + BN_EPS) * g[c];
        scsh[c]      = sc;
        scsh[64 + c] = beta[c] - m * sc;
    }
}

// ---------------------------------------------------------------------------
// CSR build
// ---------------------------------------------------------------------------
__global__ __launch_bounds__(256) void k_deg(const int* __restrict__ dst,
                                             int* __restrict__ indeg) {
    int e = blockIdx.x * 256 + threadIdx.x;
    if (e < N_EDGES) atomicAdd(&indeg[dst[e]], 1);
}

__global__ __launch_bounds__(256) void k_scanpart(const int* __restrict__ indeg,
                                                  int* __restrict__ bsum) {
    __shared__ int s[256];
    int i = blockIdx.x * 256 + threadIdx.x;
    s[threadIdx.x] = (i < N_NODES) ? indeg[i] : 0;
    __syncthreads();
    for (int off = 128; off > 0; off >>= 1) {
        if (threadIdx.x < off) s[threadIdx.x] += s[threadIdx.x + off];
        __syncthreads();
    }
    if (threadIdx.x == 0) bsum[blockIdx.x] = s[0];
}

__global__ __launch_bounds__(512) void k_scanmid(int* __restrict__ bsum, int nblk) {
    __shared__ int s[512];
    int t = threadIdx.x;
    int v = (t < nblk) ? bsum[t] : 0;
    s[t] = v;
    __syncthreads();
    for (int off = 1; off < 512; off <<= 1) {
        int x = (t >= off) ? s[t - off] : 0;
        __syncthreads();
        s[t] += x;
        __syncthreads();
    }
    if (t < nblk) bsum[t] = s[t] - v;   // exclusive
}

// scanfinal + dinv fused (both node-wise over indeg)
__global__ __launch_bounds__(256) void k_scanfinal(const int* __restrict__ indeg,
                                                   const int* __restrict__ bsum,
                                                   int* __restrict__ rowptr,
                                                   float* __restrict__ dinv) {
    __shared__ int s[256];
    int t = threadIdx.x;
    int i = blockIdx.x * 256 + t;
    int v = (i < N_NODES) ? indeg[i] : 0;
    s[t] = v;
    __syncthreads();
    for (int off = 1; off < 256; off <<= 1) {
        int x = (t >= off) ? s[t - off] : 0;
        __syncthreads();
        s[t] += x;
        __syncthreads();
    }
    if (i < N_NODES) {
        rowptr[i] = bsum[blockIdx.x] + s[t] - v;
        dinv[i]   = rsqrtf((float)v + 1.f);
    }
    if (i == 0) rowptr[N_NODES] = N_EDGES;
}

__global__ __launch_bounds__(256) void k_fill(const int* __restrict__ src,
                                              const int* __restrict__ dst,
                                              const int* __restrict__ rowptr,
                                              int* __restrict__ indeg,
                                              int* __restrict__ colidx) {
    int e = blockIdx.x * 256 + threadIdx.x;
    if (e >= N_EDGES) return;
    int d = dst[e];
    int pos = rowptr[d] + (atomicSub(&indeg[d], 1) - 1);
    colidx[pos] = src[e];
}

// ---------------------------------------------------------------------------
// Fused gather + conv finalize: one wave per dst node, 8 edge-slots x 8
// col-lanes x bf16x8 (16B/lane). HW, Hin, Out all bf16; accumulation fp32.
// ---------------------------------------------------------------------------
template <int IN_MODE, bool RELU>
__global__ __launch_bounds__(256) void k_gather(const int* __restrict__ rowptr,
                                                const int* __restrict__ colidx,
                                                const unsigned short* __restrict__ HWb,
                                                const unsigned short* __restrict__ Hin,
                                                const float* __restrict__ dinv,
                                                const float* __restrict__ bias,
                                                const float* __restrict__ scsh,
                                                unsigned short* __restrict__ Out) {
    int d = blockIdx.x * 4 + (threadIdx.x >> 6);
    if (d >= N_NODES) return;
    const int lane = threadIdx.x & 63;
    const int slot = lane >> 3;          // 0..7 edge slot
    const int c8   = (lane & 7) << 3;    // column base (8 cols per lane)
    const int j0 = rowptr[d], j1 = rowptr[d + 1];

    float acc[8];
    #pragma unroll
    for (int k = 0; k < 8; ++k) acc[k] = 0.f;

    if (slot == 7) {  // self-loop term
        uint4 v = *reinterpret_cast<const uint4*>(&HWb[(size_t)d * HID + c8]);
        acc[0] += bflo(v.x); acc[1] += bfhi(v.x);
        acc[2] += bflo(v.y); acc[3] += bfhi(v.y);
        acc[4] += bflo(v.z); acc[5] += bfhi(v.z);
        acc[6] += bflo(v.w); acc[7] += bfhi(v.w);
    }
    for (int j = j0 + slot; j < j1; j += 8) {
        int s = colidx[j];
        uint4 v = *reinterpret_cast<const uint4*>(&HWb[(size_t)s * HID + c8]);
        acc[0] += bflo(v.x); acc[1] += bfhi(v.x);
        acc[2] += bflo(v.y); acc[3] += bfhi(v.y);
        acc[4] += bflo(v.z); acc[5] += bfhi(v.z);
        acc[6] += bflo(v.w); acc[7] += bfhi(v.w);
    }
    // reduce across the 8 slots (lane bits 3,4,5)
    #pragma unroll
    for (int m = 8; m < 64; m <<= 1) {
        #pragma unroll
        for (int k = 0; k < 8; ++k) acc[k] += __shfl_xor(acc[k], m);
    }

    if (slot == 0) {
        uint4 hv = *reinterpret_cast<const uint4*>(&Hin[(size_t)d * HID + c8]);
        float h[8];
        h[0] = bflo(hv.x); h[1] = bfhi(hv.x);
        h[2] = bflo(hv.y); h[3] = bfhi(hv.y);
        h[4] = bflo(hv.z); h[5] = bfhi(hv.z);
        h[6] = bflo(hv.w); h[7] = bfhi(hv.w);
        if (IN_MODE == 1) {
            #pragma unroll
            for (int k = 0; k < 8; ++k)
                h[k] = h[k] * scsh[c8 + k] + scsh[64 + c8 + k];
        }
        float di = dinv[d];
        float o[8];
        #pragma unroll
        for (int k = 0; k < 8; ++k) {
            o[k] = acc[k] * di + bias[c8 + k] + h[k];
            if (RELU) o[k] = fmaxf(o[k], 0.f);
        }
        uint4 ov;
        ov.x = bfpack(o[0], o[1]); ov.y = bfpack(o[2], o[3]);
        ov.z = bfpack(o[4], o[5]); ov.w = bfpack(o[6], o[7]);
        *reinterpret_cast<uint4*>(&Out[(size_t)d * HID + c8]) = ov;
    }
}

// ---------------------------------------------------------------------------
// Two-stage segment-mean pool over sorted batch (stage 2 fused into k_final)
// ---------------------------------------------------------------------------
__device__ __forceinline__ int lowerb(const int* __restrict__ b, int n, int v) {
    int lo = 0, hi = n;
    while (lo < hi) { int m = (lo + hi) >> 1; if (b[m] < v) lo = m + 1; else hi = m; }
    return lo;
}

__global__ __launch_bounds__(256) void k_pool1(const unsigned short* __restrict__ Y,
                                               const int* __restrict__ batch,
                                               float* __restrict__ partial2) {
    int g  = blockIdx.x >> 4;
    int sb = blockIdx.x & 15;
    int tid = threadIdx.x, col = tid & 63, rg = tid >> 6;
    int lo = lowerb(batch, N_NODES, g);
    int hi = lowerb(batch, N_NODES, g + 1);
    int cnt = hi - lo;
    int st = lo + (int)(((long long)cnt * sb) >> 4);
    int en = lo + (int)(((long long)cnt * (sb + 1)) >> 4);
    float s = 0.f;
    for (int r = st + rg; r < en; r += 4)
        s += bflo((unsigned int)Y[(size_t)r * HID + col]);
    __shared__ float ls[4][64];
    ls[rg][col] = s;
    __syncthreads();
    if (tid < 64)
        partial2[(size_t)blockIdx.x * 64 + tid] =
            ls[0][tid] + ls[1][tid] + ls[2][tid] + ls[3][tid];
}

// ---------------------------------------------------------------------------
// Final head (pool stage-2 + final BN fused; segment bounds hoisted to LDS --
// the per-iteration lowerb in R7 serialized ~544 dependent loads = 170us)
// ---------------------------------------------------------------------------
__global__ __launch_bounds__(256) void k_final(const float* __restrict__ partial2,
                                               const int* __restrict__ batch,
                                               const float* __restrict__ scsh,
                                               const float* __restrict__ W0,
                                               const float* __restrict__ b0,
                                               const float* __restrict__ W1,
                                               const float* __restrict__ b1,
                                               const float* __restrict__ W2,
                                               const float* __restrict__ b2,
                                               float* __restrict__ out) {
    __shared__ float P[64][65];
    __shared__ float Z[64][65];
    __shared__ int sOff[NGRAPH + 1];
    int tid = threadIdx.x;
    if (tid <= NGRAPH) sOff[tid] = lowerb(batch, N_NODES, tid);  // 65 parallel searches
    __syncthreads();
    for (int i = tid; i < NGRAPH * HID; i += 256) {
        int g = i >> 6, c = i & 63;
        float S = 0.f;
        #pragma unroll
        for (int sb = 0; sb < POOL_SUB; ++sb)
            S += partial2[(size_t)(g * POOL_SUB + sb) * 64 + c];
        int cnt = sOff[g + 1] - sOff[g];
        float v = 0.f;
        if (cnt > 0) v = (S / (float)cnt) * scsh[c] + scsh[64 + c];
        P[g][c] = v;
    }
    __syncthreads();
    for (int t = 0; t < 16; ++t) {
        int o = tid + 256 * t; int r = o >> 6, c = o & 63;
        float acc = b0[c];
        #pragma unroll 8
        for (int k = 0; k < 64; ++k) acc += P[r][k] * W0[k * 64 + c];
        Z[r][c] = fmaxf(acc, 0.f);
    }
    __syncthreads();
    for (int t = 0; t < 16; ++t) {
        int o = tid + 256 * t; int r = o >> 6, c = o & 63;
        float acc = b1[c];
        #pragma unroll 8
        for (int k = 0; k < 64; ++k) acc += Z[r][k] * W1[k * 64 + c];
        P[r][c] = fmaxf(acc, 0.f);
    }
    __syncthreads();
    if (tid < NGRAPH * OUTC) {
        int r = tid >> 1, c = tid & 1;
        float acc = b2[c];
        #pragma unroll 8
        for (int k = 0; k < 64; ++k) acc += P[r][k] * W2[k * OUTC + c];
        out[tid] = acc;
    }
}

// ---------------------------------------------------------------------------
extern "C" void kernel_launch(void* const* d_in, const int* in_sizes, int n_in,
                              void* d_out, int out_size, void* d_ws, size_t ws_size,
                              hipStream_t stream) {
    const float* x        = (const float*)d_in[0];
    const int*   ei       = (const int*)d_in[1];
    const int*   batch    = (const int*)d_in[2];
    const float* pre_W    = (const float*)d_in[3];
    const float* pre_b    = (const float*)d_in[4];
    const float* pre_g    = (const float*)d_in[5];
    const float* pre_beta = (const float*)d_in[6];
    const float* conv_W   = (const float*)d_in[7];
    const float* conv_b   = (const float*)d_in[8];
    const float* post_W   = (const float*)d_in[9];
    const float* post_b   = (const float*)d_in[10];
    const float* post_g   = (const float*)d_in[11];
    const float* post_beta= (const float*)d_in[12];
    const float* fW0 = (const float*)d_in[13];
    const float* fb0 = (const float*)d_in[14];
    const float* fW1 = (const float*)d_in[15];
    const float* fb1 = (const float*)d_in[16];
    const float* fW2 = (const float*)d_in[17];
    const float* fb2 = (const float*)d_in[18];
    float* out = (float*)d_out;

    const size_t NH = (size_t)N_NODES * HID;
    float* ws       = (float*)d_ws;
    float* A        = ws;              // bf16 trunk buffer (NH ushorts)
    float* B        = A + NH;          // bf16 HW buffer (NH ushorts)
    float* C        = B + NH;          // bf16 trunk buffer (NH ushorts)
    float* dinv     = C + NH;                         // N
    float* partial  = dinv + N_NODES;                 // GEMM_BLK*128
    float* scsh     = partial + (size_t)GEMM_BLK*128; // 6 slots of 128
    float* partial2 = scsh + 6 * 128;                 // 1024*64
    int*   indeg    = (int*)(partial2 + NGRAPH * POOL_SUB * 64);
    int*   rowptr   = indeg + N_NODES;                // N+1
    int*   colidx   = rowptr + N_NODES + 1;           // E
    int*   bsum     = colidx + N_EDGES;               // NSCAN_BLK
    unsigned short* Ab  = (unsigned short*)A;
    unsigned short* Bb  = (unsigned short*)B;
    unsigned short* Cb  = (unsigned short*)C;

    const int* srcp = ei;
    const int* dstp = ei + N_EDGES;

    const int gEdge  = (N_EDGES + 255) / 256;
    const int gNode4 = (N_NODES + 3) / 4;

    // ---- CSR build ----
    hipMemsetAsync(indeg, 0, N_NODES * sizeof(int), stream);
    k_deg<<<gEdge, 256, 0, stream>>>(dstp, indeg);
    k_scanpart<<<NSCAN_BLK, 256, 0, stream>>>(indeg, bsum);
    k_scanmid<<<1, 512, 0, stream>>>(bsum, NSCAN_BLK);
    k_scanfinal<<<NSCAN_BLK, 256, 0, stream>>>(indeg, bsum, rowptr, dinv);
    k_fill<<<gEdge, 256, 0, stream>>>(srcp, dstp, rowptr, indeg, colidx);

    // ---- pre-processing: GEMM(+fused prev BN/ReLU, +stats) ----
    k_gemm<0, true,  true, false, true><<<GEMM_BLK, 256, 0, stream>>>(x, pre_W, pre_b, nullptr, nullptr, Ab, partial, N_NODES);
    k_statsfin<<<64, 256, 0, stream>>>(partial, pre_g, pre_beta, scsh + 0 * 128, N_NODES);

    k_gemm<2, false, true, false, true><<<GEMM_BLK, 256, 0, stream>>>(Ab, pre_W + 4096, pre_b + 64, nullptr, scsh + 0 * 128, Cb, partial, N_NODES);
    k_statsfin<<<64, 256, 0, stream>>>(partial, pre_g + 64, pre_beta + 64, scsh + 1 * 128, N_NODES);

    k_gemm<2, false, true, false, true><<<GEMM_BLK, 256, 0, stream>>>(Cb, pre_W + 2 * 4096, pre_b + 128, nullptr, scsh + 1 * 128, Ab, partial, N_NODES);
    k_statsfin<<<64, 256, 0, stream>>>(partial, pre_g + 128, pre_beta + 128, scsh + 2 * 128, N_NODES);

    // ---- GCNConv stack (all buffers bf16) ----
    for (int i = 0; i < 6; ++i) {
        const unsigned short* in = (i & 1) ? Cb : Ab;
        unsigned short*     outb = (i & 1) ? Ab : Cb;
        const float* Wl = conv_W + i * 4096;
        const float* bl = conv_b + i * 64;
        if (i == 0)
            k_gemm<1, false, false, true, false><<<GEMM_BLK, 256, 0, stream>>>(in, Wl, nullptr, dinv, scsh + 2 * 128, Bb, nullptr, N_NODES);
        else
            k_gemm<0, false, false, true, false><<<GEMM_BLK, 256, 0, stream>>>(in, Wl, nullptr, dinv, nullptr, Bb, nullptr, N_NODES);

        if (i == 0)
            k_gather<1, true ><<<gNode4, 256, 0, stream>>>(rowptr, colidx, Bb, in, dinv, bl, scsh + 2 * 128, outb);
        else if (i != 5)
            k_gather<0, true ><<<gNode4, 256, 0, stream>>>(rowptr, colidx, Bb, in, dinv, bl, nullptr, outb);
        else
            k_gather<0, false><<<gNode4, 256, 0, stream>>>(rowptr, colidx, Bb, in, dinv, bl, nullptr, outb);
    }
    // conv output in Ab (i=5 odd -> outb=Ab)

    // ---- post-processing ----
    k_gemm<0, false, true, false, true><<<GEMM_BLK, 256, 0, stream>>>(Ab, post_W, post_b, nullptr, nullptr, Cb, partial, N_NODES);
    k_statsfin<<<64, 256, 0, stream>>>(partial, post_g, post_beta, scsh + 3 * 128, N_NODES);

    k_gemm<2, false, true, false, true><<<GEMM_BLK, 256, 0, stream>>>(Cb, post_W + 4096, post_b + 64, nullptr, scsh + 3 * 128, Ab, partial, N_NODES);
    k_statsfin<<<64, 256, 0, stream>>>(partial, post_g + 64, post_beta + 64, scsh + 4 * 128, N_NODES);

    k_gemm<2, false, true, false, true><<<GEMM_BLK, 256, 0, stream>>>(Ab, post_W + 2 * 4096, post_b + 128, nullptr, scsh + 4 * 128, Cb, partial, N_NODES);
    k_statsfin<<<64, 256, 0, stream>>>(partial, post_g + 128, post_beta + 128, scsh + 5 * 128, N_NODES);

    // ---- pool stage 1 + fused(pool2 + BN + head) ----
    k_pool1<<<NGRAPH * POOL_SUB, 256, 0, stream>>>(Cb, batch, partial2);
    k_final<<<1, 256, 0, stream>>>(partial2, batch, scsh + 5 * 128,
                                   fW0, fb0, fW1, fb1, fW2, fb2, out);
}

// Round 9
// 534.442 us; speedup vs baseline: 1.2209x; 1.0727x over previous
//
#include <hip/hip_runtime.h>

#define N_NODES 100000
#define N_EDGES 800000
#define HID 64
#define NGRAPH 64
#define OUTC 2
#define BN_EPS 1e-5f
#define GEMM_BLK ((N_NODES + 63) / 64)      // 1563
#define POOL_SUB 16
// bucket-sorted CSR build
#define BSHIFT 11
#define NBUCK 64
#define NBUCK_ACT ((N_NODES + (1 << BSHIFT) - 1) >> BSHIFT)   // 49
#define NEB_BLK ((N_EDGES + 2047) / 2048)                      // 391

typedef __attribute__((ext_vector_type(8))) short bf16x8;
typedef __attribute__((ext_vector_type(4))) float f32x4;

__device__ __forceinline__ unsigned short f2bf(float f) {
    unsigned int u = __float_as_uint(f);
    u = (u + 0x7FFFu + ((u >> 16) & 1u)) >> 16;   // round-to-nearest-even
    return (unsigned short)u;
}
__device__ __forceinline__ float bflo(unsigned int u) { return __uint_as_float(u << 16); }
__device__ __forceinline__ float bfhi(unsigned int u) { return __uint_as_float(u & 0xFFFF0000u); }
__device__ __forceinline__ unsigned int bfpack(float a, float b) {
    return (unsigned int)f2bf(a) | ((unsigned int)f2bf(b) << 16);
}

// ---------------------------------------------------------------------------
// GEMM via bf16 MFMA (unchanged from R8)
// ---------------------------------------------------------------------------
template <int IN_MODE, bool IN_FP32, bool ADD_BIAS, bool ROW_SCALE, bool STATS>
__global__ __launch_bounds__(256) void k_gemm(const void* __restrict__ Xv,
                                              const float* __restrict__ W,
                                              const float* __restrict__ bias,
                                              const float* __restrict__ dinv,
                                              const float* __restrict__ scsh,
                                              unsigned short* __restrict__ Y,
                                              float* __restrict__ partial, int n) {
    __shared__ __align__(16) unsigned short sXb[64][72];
    __shared__ __align__(16) unsigned short sWT[64][72];
    __shared__ float sDinv[64];
    const int tid  = threadIdx.x;
    const int row0 = blockIdx.x * 64;

    #pragma unroll
    for (int i = tid; i < 1024; i += 256) {
        int k = i >> 4, c4 = (i & 15) << 2;
        float4 w = *reinterpret_cast<const float4*>(&W[k * 64 + c4]);
        sWT[c4 + 0][k] = f2bf(w.x);
        sWT[c4 + 1][k] = f2bf(w.y);
        sWT[c4 + 2][k] = f2bf(w.z);
        sWT[c4 + 3][k] = f2bf(w.w);
    }
    if (IN_FP32) {
        const float* X = (const float*)Xv;
        #pragma unroll
        for (int f = tid; f < 1024; f += 256) {
            int r = f >> 4, c4 = (f & 15) << 2;
            float4 v = make_float4(0.f, 0.f, 0.f, 0.f);
            if (row0 + r < n)
                v = *reinterpret_cast<const float4*>(&X[(size_t)(row0 + r) * HID + c4]);
            if (IN_MODE >= 1) {
                float4 sc = *reinterpret_cast<const float4*>(&scsh[c4]);
                float4 sh = *reinterpret_cast<const float4*>(&scsh[64 + c4]);
                v.x = v.x * sc.x + sh.x; v.y = v.y * sc.y + sh.y;
                v.z = v.z * sc.z + sh.z; v.w = v.w * sc.w + sh.w;
                if (IN_MODE == 2) {
                    v.x = fmaxf(v.x, 0.f); v.y = fmaxf(v.y, 0.f);
                    v.z = fmaxf(v.z, 0.f); v.w = fmaxf(v.w, 0.f);
                }
            }
            sXb[r][c4 + 0] = f2bf(v.x);
            sXb[r][c4 + 1] = f2bf(v.y);
            sXb[r][c4 + 2] = f2bf(v.z);
            sXb[r][c4 + 3] = f2bf(v.w);
        }
    } else {
        const unsigned short* X = (const unsigned short*)Xv;
        #pragma unroll
        for (int f = tid; f < 512; f += 256) {
            int r = f >> 3, c8 = (f & 7) << 3;
            uint4 u = make_uint4(0u, 0u, 0u, 0u);
            if (row0 + r < n)
                u = *reinterpret_cast<const uint4*>(&X[(size_t)(row0 + r) * HID + c8]);
            if (IN_MODE >= 1) {
                float v[8];
                v[0] = bflo(u.x); v[1] = bfhi(u.x);
                v[2] = bflo(u.y); v[3] = bfhi(u.y);
                v[4] = bflo(u.z); v[5] = bfhi(u.z);
                v[6] = bflo(u.w); v[7] = bfhi(u.w);
                #pragma unroll
                for (int k = 0; k < 8; ++k) {
                    v[k] = v[k] * scsh[c8 + k] + scsh[64 + c8 + k];
                    if (IN_MODE == 2) v[k] = fmaxf(v[k], 0.f);
                }
                u.x = bfpack(v[0], v[1]); u.y = bfpack(v[2], v[3]);
                u.z = bfpack(v[4], v[5]); u.w = bfpack(v[6], v[7]);
            }
            *reinterpret_cast<uint4*>(&sXb[r][c8]) = u;
        }
    }
    if (ROW_SCALE && tid < 64)
        sDinv[tid] = (row0 + tid < n) ? dinv[row0 + tid] : 0.f;
    __syncthreads();

    const int lane = tid & 63;
    const int wv   = tid >> 6;
    const int cl   = lane & 15;
    const int kg   = lane >> 4;
    const int col  = (wv << 4) + cl;

    const f32x4 zero = {0.f, 0.f, 0.f, 0.f};
    f32x4 acc[4];
    #pragma unroll
    for (int m = 0; m < 4; ++m) acc[m] = zero;

    #pragma unroll
    for (int k0 = 0; k0 < 64; k0 += 32) {
        bf16x8 bfrag = *reinterpret_cast<const bf16x8*>(&sWT[col][k0 + (kg << 3)]);
        #pragma unroll
        for (int m = 0; m < 4; ++m) {
            bf16x8 afrag = *reinterpret_cast<const bf16x8*>(&sXb[(m << 4) + cl][k0 + (kg << 3)]);
            acc[m] = __builtin_amdgcn_mfma_f32_16x16x32_bf16(afrag, bfrag, acc[m], 0, 0, 0);
        }
    }

    const float bb = ADD_BIAS ? bias[col] : 0.f;
    float colS = 0.f, colQ = 0.f;
    #pragma unroll
    for (int m = 0; m < 4; ++m) {
        #pragma unroll
        for (int j = 0; j < 4; ++j) {
            int rl = (m << 4) + (kg << 2) + j;
            int r  = row0 + rl;
            if (r < n) {
                float s = ROW_SCALE ? sDinv[rl] : 1.f;
                float o = acc[m][j] * s + bb;
                Y[(size_t)r * HID + col] = f2bf(o);
                if (STATS) { colS += o; colQ += o * o; }
            }
        }
    }
    if (STATS) {
        colS += __shfl_xor(colS, 16); colQ += __shfl_xor(colQ, 16);
        colS += __shfl_xor(colS, 32); colQ += __shfl_xor(colQ, 32);
        if (kg == 0) {
            partial[blockIdx.x * 128 + col]      = colS;
            partial[blockIdx.x * 128 + 64 + col] = colQ;
        }
    }
}

// Reduce per-block partials -> scale/shift. One block per column.
__global__ __launch_bounds__(256) void k_statsfin(const float* __restrict__ partial,
                                                  const float* __restrict__ g,
                                                  const float* __restrict__ beta,
                                                  float* __restrict__ scsh, int n) {
    int c = blockIdx.x, t = threadIdx.x;
    float S = 0.f, Q = 0.f;
    for (int b = t; b < GEMM_BLK; b += 256) {
        S += partial[b * 128 + c];
        Q += partial[b * 128 + 64 + c];
    }
    __shared__ float ss[256], sq[256];
    ss[t] = S; sq[t] = Q;
    __syncthreads();
    for (int off = 128; off > 0; off >>= 1) {
        if (t < off) { ss[t] += ss[t + off]; sq[t] += sq[t + off]; }
        __syncthreads();
    }
    if (t == 0) {
        float nf = (float)n;
        float m  = ss[0] / nf;
        float v  = sq[0] / nf - m * m;
        float sc = rsqrtf(v + BN_EPS) * g[c];
        scsh[c]      = sc;
        scsh[64 + c] = beta[c] - m * sc;
    }
}

// ---------------------------------------------------------------------------
// Bucket-sorted CSR build (replaces deg/scan/fill; no global atomics).
// Buckets of 2048 nodes (dst>>11). Same-line colidx writes now come from one
// block close in time -> L2 write-combining (old k_fill: 58MB writeback for
// a 3.2MB payload).
// ---------------------------------------------------------------------------
__global__ __launch_bounds__(256) void k_hist(const int* __restrict__ dst,
                                              int* __restrict__ histmat) {
    __shared__ int lh[NBUCK];
    int t = threadIdx.x;
    if (t < NBUCK) lh[t] = 0;
    __syncthreads();
    int base = blockIdx.x * 2048;
    for (int i = t; i < 2048; i += 256) {
        int e = base + i;
        if (e < N_EDGES) atomicAdd(&lh[dst[e] >> BSHIFT], 1);
    }
    __syncthreads();
    if (t < NBUCK) histmat[blockIdx.x * NBUCK + t] = lh[t];
}

// one block: per-(block,bucket) exclusive offsets + bucket bases
__global__ __launch_bounds__(256) void k_escan(const int* __restrict__ histmat,
                                               int* __restrict__ blockoff,
                                               int* __restrict__ bucketbase) {
    __shared__ int csum[4][NBUCK];
    __shared__ int cbase[4][NBUCK];
    __shared__ int tot[NBUCK + 1];
    int t = threadIdx.x;
    int b = t & 63, c = t >> 6;
    const int CHUNK = (NEB_BLK + 3) / 4;          // 98
    int lo = c * CHUNK, hi = min(lo + CHUNK, NEB_BLK);
    int s = 0;
    #pragma unroll 8
    for (int blk = lo; blk < hi; ++blk) s += histmat[blk * NBUCK + b];
    csum[c][b] = s;
    __syncthreads();
    if (t < NBUCK) {
        int r = 0;
        #pragma unroll
        for (int c2 = 0; c2 < 4; ++c2) { cbase[c2][t] = r; r += csum[c2][t]; }
        tot[t] = r;
    }
    __syncthreads();
    if (t == 0) {
        int r = 0;
        for (int b2 = 0; b2 < NBUCK; ++b2) { int v = tot[b2]; tot[b2] = r; r += v; }
        tot[NBUCK] = r;                            // == N_EDGES
    }
    __syncthreads();
    if (t <= NBUCK) bucketbase[t] = tot[t];
    int r = cbase[c][b];
    #pragma unroll 8
    for (int blk = lo; blk < hi; ++blk) {
        blockoff[blk * NBUCK + b] = r;
        r += histmat[blk * NBUCK + b];
    }
}

__global__ __launch_bounds__(256) void k_reorder(const int* __restrict__ src,
                                                 const int* __restrict__ dst,
                                                 const int* __restrict__ blockoff,
                                                 const int* __restrict__ bucketbase,
                                                 int2* __restrict__ esort) {
    __shared__ int lcur[NBUCK];
    int t = threadIdx.x;
    if (t < NBUCK) lcur[t] = 0;
    __syncthreads();
    int base = blockIdx.x * 2048;
    for (int i = t; i < 2048; i += 256) {
        int e = base + i;
        if (e < N_EDGES) {
            int d = dst[e];
            int b = d >> BSHIFT;
            int r = atomicAdd(&lcur[b], 1);
            esort[bucketbase[b] + blockoff[blockIdx.x * NBUCK + b] + r] =
                make_int2(src[e], d);
        }
    }
}

// one block per bucket: per-node counts (LDS), scan -> rowptr/dinv, fill colidx
__global__ __launch_bounds__(256) void k_csr(const int2* __restrict__ esort,
                                             const int* __restrict__ bucketbase,
                                             int* __restrict__ rowptr,
                                             int* __restrict__ colidx,
                                             float* __restrict__ dinv) {
    __shared__ int lh[1 << BSHIFT];
    __shared__ int ctot[256];
    int t = threadIdx.x;
    int b = blockIdx.x;
    int node0 = b << BSHIFT;
    int nNodes = min(1 << BSHIFT, N_NODES - node0);
    int e0 = bucketbase[b], e1 = bucketbase[b + 1];
    #pragma unroll
    for (int i = t; i < (1 << BSHIFT); i += 256) lh[i] = 0;
    __syncthreads();
    for (int e = e0 + t; e < e1; e += 256)
        atomicAdd(&lh[esort[e].y - node0], 1);
    __syncthreads();
    // exclusive scan over 2048 counts: per-thread 8-chunk + Hillis-Steele
    int c0 = t * 8;
    int cnt[8];
    int s = 0;
    #pragma unroll
    for (int j = 0; j < 8; ++j) { cnt[j] = lh[c0 + j]; s += cnt[j]; }
    ctot[t] = s;
    __syncthreads();
    int v = ctot[t];
    for (int off = 1; off < 256; off <<= 1) {
        int x = (t >= off) ? ctot[t - off] : 0;
        __syncthreads();
        ctot[t] += x;
        __syncthreads();
    }
    int run = ctot[t] - v;                       // exclusive chunk prefix
    #pragma unroll
    for (int j = 0; j < 8; ++j) {
        int idx = c0 + j;
        int cv = cnt[j];
        lh[idx] = run;                            // cursor start
        if (idx < nNodes) {
            rowptr[node0 + idx] = e0 + run;
            dinv[node0 + idx]   = rsqrtf((float)cv + 1.f);
        }
        run += cv;
    }
    __syncthreads();
    for (int e = e0 + t; e < e1; e += 256) {
        int2 ed = esort[e];
        int r = atomicAdd(&lh[ed.y - node0], 1);
        colidx[e0 + r] = ed.x;
    }
    if (b == 0 && t == 0) rowptr[N_NODES] = N_EDGES;
}

// ---------------------------------------------------------------------------
// Fused gather + conv finalize (unchanged from R8)
// ---------------------------------------------------------------------------
template <int IN_MODE, bool RELU>
__global__ __launch_bounds__(256) void k_gather(const int* __restrict__ rowptr,
                                                const int* __restrict__ colidx,
                                                const unsigned short* __restrict__ HWb,
                                                const unsigned short* __restrict__ Hin,
                                                const float* __restrict__ dinv,
                                                const float* __restrict__ bias,
                                                const float* __restrict__ scsh,
                                                unsigned short* __restrict__ Out) {
    int d = blockIdx.x * 4 + (threadIdx.x >> 6);
    if (d >= N_NODES) return;
    const int lane = threadIdx.x & 63;
    const int slot = lane >> 3;
    const int c8   = (lane & 7) << 3;
    const int j0 = rowptr[d], j1 = rowptr[d + 1];

    float acc[8];
    #pragma unroll
    for (int k = 0; k < 8; ++k) acc[k] = 0.f;

    if (slot == 7) {
        uint4 v = *reinterpret_cast<const uint4*>(&HWb[(size_t)d * HID + c8]);
        acc[0] += bflo(v.x); acc[1] += bfhi(v.x);
        acc[2] += bflo(v.y); acc[3] += bfhi(v.y);
        acc[4] += bflo(v.z); acc[5] += bfhi(v.z);
        acc[6] += bflo(v.w); acc[7] += bfhi(v.w);
    }
    for (int j = j0 + slot; j < j1; j += 8) {
        int s = colidx[j];
        uint4 v = *reinterpret_cast<const uint4*>(&HWb[(size_t)s * HID + c8]);
        acc[0] += bflo(v.x); acc[1] += bfhi(v.x);
        acc[2] += bflo(v.y); acc[3] += bfhi(v.y);
        acc[4] += bflo(v.z); acc[5] += bfhi(v.z);
        acc[6] += bflo(v.w); acc[7] += bfhi(v.w);
    }
    #pragma unroll
    for (int m = 8; m < 64; m <<= 1) {
        #pragma unroll
        for (int k = 0; k < 8; ++k) acc[k] += __shfl_xor(acc[k], m);
    }

    if (slot == 0) {
        uint4 hv = *reinterpret_cast<const uint4*>(&Hin[(size_t)d * HID + c8]);
        float h[8];
        h[0] = bflo(hv.x); h[1] = bfhi(hv.x);
        h[2] = bflo(hv.y); h[3] = bfhi(hv.y);
        h[4] = bflo(hv.z); h[5] = bfhi(hv.z);
        h[6] = bflo(hv.w); h[7] = bfhi(hv.w);
        if (IN_MODE == 1) {
            #pragma unroll
            for (int k = 0; k < 8; ++k)
                h[k] = h[k] * scsh[c8 + k] + scsh[64 + c8 + k];
        }
        float di = dinv[d];
        float o[8];
        #pragma unroll
        for (int k = 0; k < 8; ++k) {
            o[k] = acc[k] * di + bias[c8 + k] + h[k];
            if (RELU) o[k] = fmaxf(o[k], 0.f);
        }
        uint4 ov;
        ov.x = bfpack(o[0], o[1]); ov.y = bfpack(o[2], o[3]);
        ov.z = bfpack(o[4], o[5]); ov.w = bfpack(o[6], o[7]);
        *reinterpret_cast<uint4*>(&Out[(size_t)d * HID + c8]) = ov;
    }
}

// ---------------------------------------------------------------------------
// Two-stage segment-mean pool over sorted batch (stage 2 fused into k_final)
// ---------------------------------------------------------------------------
__device__ __forceinline__ int lowerb(const int* __restrict__ b, int n, int v) {
    int lo = 0, hi = n;
    while (lo < hi) { int m = (lo + hi) >> 1; if (b[m] < v) lo = m + 1; else hi = m; }
    return lo;
}

__global__ __launch_bounds__(256) void k_pool1(const unsigned short* __restrict__ Y,
                                               const int* __restrict__ batch,
                                               float* __restrict__ partial2) {
    int g  = blockIdx.x >> 4;
    int sb = blockIdx.x & 15;
    int tid = threadIdx.x, col = tid & 63, rg = tid >> 6;
    int lo = lowerb(batch, N_NODES, g);
    int hi = lowerb(batch, N_NODES, g + 1);
    int cnt = hi - lo;
    int st = lo + (int)(((long long)cnt * sb) >> 4);
    int en = lo + (int)(((long long)cnt * (sb + 1)) >> 4);
    float s = 0.f;
    for (int r = st + rg; r < en; r += 4)
        s += bflo((unsigned int)Y[(size_t)r * HID + col]);
    __shared__ float ls[4][64];
    ls[rg][col] = s;
    __syncthreads();
    if (tid < 64)
        partial2[(size_t)blockIdx.x * 64 + tid] =
            ls[0][tid] + ls[1][tid] + ls[2][tid] + ls[3][tid];
}

// ---------------------------------------------------------------------------
// Final head (pool stage-2 + final BN fused; segment bounds hoisted to LDS)
// ---------------------------------------------------------------------------
__global__ __launch_bounds__(256) void k_final(const float* __restrict__ partial2,
                                               const int* __restrict__ batch,
                                               const float* __restrict__ scsh,
                                               const float* __restrict__ W0,
                                               const float* __restrict__ b0,
                                               const float* __restrict__ W1,
                                               const float* __restrict__ b1,
                                               const float* __restrict__ W2,
                                               const float* __restrict__ b2,
                                               float* __restrict__ out) {
    __shared__ float P[64][65];
    __shared__ float Z[64][65];
    __shared__ int sOff[NGRAPH + 1];
    int tid = threadIdx.x;
    if (tid <= NGRAPH) sOff[tid] = lowerb(batch, N_NODES, tid);
    __syncthreads();
    for (int i = tid; i < NGRAPH * HID; i += 256) {
        int g = i >> 6, c = i & 63;
        float S = 0.f;
        #pragma unroll
        for (int sb = 0; sb < POOL_SUB; ++sb)
            S += partial2[(size_t)(g * POOL_SUB + sb) * 64 + c];
        int cnt = sOff[g + 1] - sOff[g];
        float v = 0.f;
        if (cnt > 0) v = (S / (float)cnt) * scsh[c] + scsh[64 + c];
        P[g][c] = v;
    }
    __syncthreads();
    for (int t = 0; t < 16; ++t) {
        int o = tid + 256 * t; int r = o >> 6, c = o & 63;
        float acc = b0[c];
        #pragma unroll 8
        for (int k = 0; k < 64; ++k) acc += P[r][k] * W0[k * 64 + c];
        Z[r][c] = fmaxf(acc, 0.f);
    }
    __syncthreads();
    for (int t = 0; t < 16; ++t) {
        int o = tid + 256 * t; int r = o >> 6, c = o & 63;
        float acc = b1[c];
        #pragma unroll 8
        for (int k = 0; k < 64; ++k) acc += Z[r][k] * W1[k * 64 + c];
        P[r][c] = fmaxf(acc, 0.f);
    }
    __syncthreads();
    if (tid < NGRAPH * OUTC) {
        int r = tid >> 1, c = tid & 1;
        float acc = b2[c];
        #pragma unroll 8
        for (int k = 0; k < 64; ++k) acc += P[r][k] * W2[k * OUTC + c];
        out[tid] = acc;
    }
}

// ---------------------------------------------------------------------------
extern "C" void kernel_launch(void* const* d_in, const int* in_sizes, int n_in,
                              void* d_out, int out_size, void* d_ws, size_t ws_size,
                              hipStream_t stream) {
    const float* x        = (const float*)d_in[0];
    const int*   ei       = (const int*)d_in[1];
    const int*   batch    = (const int*)d_in[2];
    const float* pre_W    = (const float*)d_in[3];
    const float* pre_b    = (const float*)d_in[4];
    const float* pre_g    = (const float*)d_in[5];
    const float* pre_beta = (const float*)d_in[6];
    const float* conv_W   = (const float*)d_in[7];
    const float* conv_b   = (const float*)d_in[8];
    const float* post_W   = (const float*)d_in[9];
    const float* post_b   = (const float*)d_in[10];
    const float* post_g   = (const float*)d_in[11];
    const float* post_beta= (const float*)d_in[12];
    const float* fW0 = (const float*)d_in[13];
    const float* fb0 = (const float*)d_in[14];
    const float* fW1 = (const float*)d_in[15];
    const float* fb1 = (const float*)d_in[16];
    const float* fW2 = (const float*)d_in[17];
    const float* fb2 = (const float*)d_in[18];
    float* out = (float*)d_out;

    const size_t NH = (size_t)N_NODES * HID;
    unsigned short* Ab = (unsigned short*)d_ws;       // NH bf16
    unsigned short* Bb = Ab + NH;                     // NH bf16 (HW)
    unsigned short* Cb = Bb + NH;                     // NH bf16
    float* dinv     = (float*)(Cb + NH);              // N
    float* partial  = dinv + N_NODES;                 // GEMM_BLK*128
    float* scsh     = partial + (size_t)GEMM_BLK*128; // 6 slots of 128
    float* partial2 = scsh + 6 * 128;                 // 1024*64
    int* histmat    = (int*)(partial2 + NGRAPH * POOL_SUB * 64); // NEB_BLK*NBUCK
    int* blockoff   = histmat + NEB_BLK * NBUCK;      // NEB_BLK*NBUCK
    int* bucketbase = blockoff + NEB_BLK * NBUCK;     // NBUCK+1
    int* rowptr     = bucketbase + NBUCK + 1;         // N+1
    int* colidx     = rowptr + N_NODES + 1;           // E
    // keep esort 8B-aligned
    size_t eoff = (size_t)(colidx + N_EDGES - (int*)d_ws);
    eoff = (eoff + 1) & ~(size_t)1;
    int2* esort     = (int2*)((int*)d_ws + eoff);     // E int2

    const int* srcp = ei;
    const int* dstp = ei + N_EDGES;
    const int gNode4 = (N_NODES + 3) / 4;

    // ---- bucket-sorted CSR build (no global atomics) ----
    k_hist<<<NEB_BLK, 256, 0, stream>>>(dstp, histmat);
    k_escan<<<1, 256, 0, stream>>>(histmat, blockoff, bucketbase);
    k_reorder<<<NEB_BLK, 256, 0, stream>>>(srcp, dstp, blockoff, bucketbase, esort);
    k_csr<<<NBUCK_ACT, 256, 0, stream>>>(esort, bucketbase, rowptr, colidx, dinv);

    // ---- pre-processing: GEMM(+fused prev BN/ReLU, +stats) ----
    k_gemm<0, true,  true, false, true><<<GEMM_BLK, 256, 0, stream>>>(x, pre_W, pre_b, nullptr, nullptr, Ab, partial, N_NODES);
    k_statsfin<<<64, 256, 0, stream>>>(partial, pre_g, pre_beta, scsh + 0 * 128, N_NODES);

    k_gemm<2, false, true, false, true><<<GEMM_BLK, 256, 0, stream>>>(Ab, pre_W + 4096, pre_b + 64, nullptr, scsh + 0 * 128, Cb, partial, N_NODES);
    k_statsfin<<<64, 256, 0, stream>>>(partial, pre_g + 64, pre_beta + 64, scsh + 1 * 128, N_NODES);

    k_gemm<2, false, true, false, true><<<GEMM_BLK, 256, 0, stream>>>(Cb, pre_W + 2 * 4096, pre_b + 128, nullptr, scsh + 1 * 128, Ab, partial, N_NODES);
    k_statsfin<<<64, 256, 0, stream>>>(partial, pre_g + 128, pre_beta + 128, scsh + 2 * 128, N_NODES);

    // ---- GCNConv stack (all buffers bf16) ----
    for (int i = 0; i < 6; ++i) {
        const unsigned short* in = (i & 1) ? Cb : Ab;
        unsigned short*     outb = (i & 1) ? Ab : Cb;
        const float* Wl = conv_W + i * 4096;
        const float* bl = conv_b + i * 64;
        if (i == 0)
            k_gemm<1, false, false, true, false><<<GEMM_BLK, 256, 0, stream>>>(in, Wl, nullptr, dinv, scsh + 2 * 128, Bb, nullptr, N_NODES);
        else
            k_gemm<0, false, false, true, false><<<GEMM_BLK, 256, 0, stream>>>(in, Wl, nullptr, dinv, nullptr, Bb, nullptr, N_NODES);

        if (i == 0)
            k_gather<1, true ><<<gNode4, 256, 0, stream>>>(rowptr, colidx, Bb, in, dinv, bl, scsh + 2 * 128, outb);
        else if (i != 5)
            k_gather<0, true ><<<gNode4, 256, 0, stream>>>(rowptr, colidx, Bb, in, dinv, bl, nullptr, outb);
        else
            k_gather<0, false><<<gNode4, 256, 0, stream>>>(rowptr, colidx, Bb, in, dinv, bl, nullptr, outb);
    }
    // conv output in Ab

    // ---- post-processing ----
    k_gemm<0, false, true, false, true><<<GEMM_BLK, 256, 0, stream>>>(Ab, post_W, post_b, nullptr, nullptr, Cb, partial, N_NODES);
    k_statsfin<<<64, 256, 0, stream>>>(partial, post_g, post_beta, scsh + 3 * 128, N_NODES);

    k_gemm<2, false, true, false, true><<<GEMM_BLK, 256, 0, stream>>>(Cb, post_W + 4096, post_b + 64, nullptr, scsh + 3 * 128, Ab, partial, N_NODES);
    k_statsfin<<<64, 256, 0, stream>>>(partial, post_g + 64, post_beta + 64, scsh + 4 * 128, N_NODES);

    k_gemm<2, false, true, false, true><<<GEMM_BLK, 256, 0, stream>>>(Ab, post_W + 2 * 4096, post_b + 128, nullptr, scsh + 4 * 128, Cb, partial, N_NODES);
    k_statsfin<<<64, 256, 0, stream>>>(partial, post_g + 128, post_beta + 128, scsh + 5 * 128, N_NODES);

    // ---- pool stage 1 + fused(pool2 + BN + head) ----
    k_pool1<<<NGRAPH * POOL_SUB, 256, 0, stream>>>(Cb, batch, partial2);
    k_final<<<1, 256, 0, stream>>>(partial2, batch, scsh + 5 * 128,
                                   fW0, fb0, fW1, fb1, fW2, fb2, out);
}

// Round 10
// 499.857 us; speedup vs baseline: 1.3054x; 1.0692x over previous
//
#include <hip/hip_runtime.h>

#define N_NODES 100000
#define N_EDGES 800000
#define HID 64
#define NGRAPH 64
#define OUTC 2
#define BN_EPS 1e-5f
#define GEMM_BLK ((N_NODES + 63) / 64)      // 1563
#define POOL_SUB 16
// bucket-sorted CSR build
#define BSHIFT 11
#define NBUCK 64
#define NBUCK_ACT ((N_NODES + (1 << BSHIFT) - 1) >> BSHIFT)   // 49
#define NEB_BLK ((N_EDGES + 2047) / 2048)                      // 391

typedef __attribute__((ext_vector_type(8))) short bf16x8;
typedef __attribute__((ext_vector_type(4))) float f32x4;
typedef __attribute__((ext_vector_type(2))) float f32x2;

__device__ __forceinline__ unsigned short f2bf(float f) {
    unsigned int u = __float_as_uint(f);
    u = (u + 0x7FFFu + ((u >> 16) & 1u)) >> 16;   // round-to-nearest-even
    return (unsigned short)u;
}
__device__ __forceinline__ float bflo(unsigned int u) { return __uint_as_float(u << 16); }
__device__ __forceinline__ float bfhi(unsigned int u) { return __uint_as_float(u & 0xFFFF0000u); }
__device__ __forceinline__ unsigned int bfpack(float a, float b) {
    return (unsigned int)f2bf(a) | ((unsigned int)f2bf(b) << 16);
}
// unpack a u32 of 2 bf16 -> (lo,hi) f32 pair
__device__ __forceinline__ f32x2 bfpair(unsigned int w) {
    f32x2 p;
    p.x = __uint_as_float(w << 16);
    p.y = __uint_as_float(w & 0xFFFF0000u);
    return p;
}
// packed f32 add (VOP3P): 2 adds in 1 instruction
__device__ __forceinline__ f32x2 pk_add(f32x2 a, f32x2 b) {
    f32x2 d;
    asm("v_pk_add_f32 %0, %1, %2" : "=v"(d) : "v"(a), "v"(b));
    return d;
}

// ---------------------------------------------------------------------------
// GEMM via bf16 MFMA (unchanged from R9)
// ---------------------------------------------------------------------------
template <int IN_MODE, bool IN_FP32, bool ADD_BIAS, bool ROW_SCALE, bool STATS>
__global__ __launch_bounds__(256) void k_gemm(const void* __restrict__ Xv,
                                              const float* __restrict__ W,
                                              const float* __restrict__ bias,
                                              const float* __restrict__ dinv,
                                              const float* __restrict__ scsh,
                                              unsigned short* __restrict__ Y,
                                              float* __restrict__ partial, int n) {
    __shared__ __align__(16) unsigned short sXb[64][72];
    __shared__ __align__(16) unsigned short sWT[64][72];
    __shared__ float sDinv[64];
    const int tid  = threadIdx.x;
    const int row0 = blockIdx.x * 64;

    #pragma unroll
    for (int i = tid; i < 1024; i += 256) {
        int k = i >> 4, c4 = (i & 15) << 2;
        float4 w = *reinterpret_cast<const float4*>(&W[k * 64 + c4]);
        sWT[c4 + 0][k] = f2bf(w.x);
        sWT[c4 + 1][k] = f2bf(w.y);
        sWT[c4 + 2][k] = f2bf(w.z);
        sWT[c4 + 3][k] = f2bf(w.w);
    }
    if (IN_FP32) {
        const float* X = (const float*)Xv;
        #pragma unroll
        for (int f = tid; f < 1024; f += 256) {
            int r = f >> 4, c4 = (f & 15) << 2;
            float4 v = make_float4(0.f, 0.f, 0.f, 0.f);
            if (row0 + r < n)
                v = *reinterpret_cast<const float4*>(&X[(size_t)(row0 + r) * HID + c4]);
            if (IN_MODE >= 1) {
                float4 sc = *reinterpret_cast<const float4*>(&scsh[c4]);
                float4 sh = *reinterpret_cast<const float4*>(&scsh[64 + c4]);
                v.x = v.x * sc.x + sh.x; v.y = v.y * sc.y + sh.y;
                v.z = v.z * sc.z + sh.z; v.w = v.w * sc.w + sh.w;
                if (IN_MODE == 2) {
                    v.x = fmaxf(v.x, 0.f); v.y = fmaxf(v.y, 0.f);
                    v.z = fmaxf(v.z, 0.f); v.w = fmaxf(v.w, 0.f);
                }
            }
            sXb[r][c4 + 0] = f2bf(v.x);
            sXb[r][c4 + 1] = f2bf(v.y);
            sXb[r][c4 + 2] = f2bf(v.z);
            sXb[r][c4 + 3] = f2bf(v.w);
        }
    } else {
        const unsigned short* X = (const unsigned short*)Xv;
        #pragma unroll
        for (int f = tid; f < 512; f += 256) {
            int r = f >> 3, c8 = (f & 7) << 3;
            uint4 u = make_uint4(0u, 0u, 0u, 0u);
            if (row0 + r < n)
                u = *reinterpret_cast<const uint4*>(&X[(size_t)(row0 + r) * HID + c8]);
            if (IN_MODE >= 1) {
                float v[8];
                v[0] = bflo(u.x); v[1] = bfhi(u.x);
                v[2] = bflo(u.y); v[3] = bfhi(u.y);
                v[4] = bflo(u.z); v[5] = bfhi(u.z);
                v[6] = bflo(u.w); v[7] = bfhi(u.w);
                #pragma unroll
                for (int k = 0; k < 8; ++k) {
                    v[k] = v[k] * scsh[c8 + k] + scsh[64 + c8 + k];
                    if (IN_MODE == 2) v[k] = fmaxf(v[k], 0.f);
                }
                u.x = bfpack(v[0], v[1]); u.y = bfpack(v[2], v[3]);
                u.z = bfpack(v[4], v[5]); u.w = bfpack(v[6], v[7]);
            }
            *reinterpret_cast<uint4*>(&sXb[r][c8]) = u;
        }
    }
    if (ROW_SCALE && tid < 64)
        sDinv[tid] = (row0 + tid < n) ? dinv[row0 + tid] : 0.f;
    __syncthreads();

    const int lane = tid & 63;
    const int wv   = tid >> 6;
    const int cl   = lane & 15;
    const int kg   = lane >> 4;
    const int col  = (wv << 4) + cl;

    const f32x4 zero = {0.f, 0.f, 0.f, 0.f};
    f32x4 acc[4];
    #pragma unroll
    for (int m = 0; m < 4; ++m) acc[m] = zero;

    #pragma unroll
    for (int k0 = 0; k0 < 64; k0 += 32) {
        bf16x8 bfrag = *reinterpret_cast<const bf16x8*>(&sWT[col][k0 + (kg << 3)]);
        #pragma unroll
        for (int m = 0; m < 4; ++m) {
            bf16x8 afrag = *reinterpret_cast<const bf16x8*>(&sXb[(m << 4) + cl][k0 + (kg << 3)]);
            acc[m] = __builtin_amdgcn_mfma_f32_16x16x32_bf16(afrag, bfrag, acc[m], 0, 0, 0);
        }
    }

    const float bb = ADD_BIAS ? bias[col] : 0.f;
    float colS = 0.f, colQ = 0.f;
    #pragma unroll
    for (int m = 0; m < 4; ++m) {
        #pragma unroll
        for (int j = 0; j < 4; ++j) {
            int rl = (m << 4) + (kg << 2) + j;
            int r  = row0 + rl;
            if (r < n) {
                float s = ROW_SCALE ? sDinv[rl] : 1.f;
                float o = acc[m][j] * s + bb;
                Y[(size_t)r * HID + col] = f2bf(o);
                if (STATS) { colS += o; colQ += o * o; }
            }
        }
    }
    if (STATS) {
        colS += __shfl_xor(colS, 16); colQ += __shfl_xor(colQ, 16);
        colS += __shfl_xor(colS, 32); colQ += __shfl_xor(colQ, 32);
        if (kg == 0) {
            partial[blockIdx.x * 128 + col]      = colS;
            partial[blockIdx.x * 128 + 64 + col] = colQ;
        }
    }
}

// Reduce per-block partials -> scale/shift. One block per column.
__global__ __launch_bounds__(256) void k_statsfin(const float* __restrict__ partial,
                                                  const float* __restrict__ g,
                                                  const float* __restrict__ beta,
                                                  float* __restrict__ scsh, int n) {
    int c = blockIdx.x, t = threadIdx.x;
    float S = 0.f, Q = 0.f;
    for (int b = t; b < GEMM_BLK; b += 256) {
        S += partial[b * 128 + c];
        Q += partial[b * 128 + 64 + c];
    }
    __shared__ float ss[256], sq[256];
    ss[t] = S; sq[t] = Q;
    __syncthreads();
    for (int off = 128; off > 0; off >>= 1) {
        if (t < off) { ss[t] += ss[t + off]; sq[t] += sq[t + off]; }
        __syncthreads();
    }
    if (t == 0) {
        float nf = (float)n;
        float m  = ss[0] / nf;
        float v  = sq[0] / nf - m * m;
        float sc = rsqrtf(v + BN_EPS) * g[c];
        scsh[c]      = sc;
        scsh[64 + c] = beta[c] - m * sc;
    }
}

// ---------------------------------------------------------------------------
// Bucket-sorted CSR build (unchanged from R9)
// ---------------------------------------------------------------------------
__global__ __launch_bounds__(256) void k_hist(const int* __restrict__ dst,
                                              int* __restrict__ histmat) {
    __shared__ int lh[NBUCK];
    int t = threadIdx.x;
    if (t < NBUCK) lh[t] = 0;
    __syncthreads();
    int base = blockIdx.x * 2048;
    for (int i = t; i < 2048; i += 256) {
        int e = base + i;
        if (e < N_EDGES) atomicAdd(&lh[dst[e] >> BSHIFT], 1);
    }
    __syncthreads();
    if (t < NBUCK) histmat[blockIdx.x * NBUCK + t] = lh[t];
}

__global__ __launch_bounds__(256) void k_escan(const int* __restrict__ histmat,
                                               int* __restrict__ blockoff,
                                               int* __restrict__ bucketbase) {
    __shared__ int csum[4][NBUCK];
    __shared__ int cbase[4][NBUCK];
    __shared__ int tot[NBUCK + 1];
    int t = threadIdx.x;
    int b = t & 63, c = t >> 6;
    const int CHUNK = (NEB_BLK + 3) / 4;          // 98
    int lo = c * CHUNK, hi = min(lo + CHUNK, NEB_BLK);
    int s = 0;
    #pragma unroll 8
    for (int blk = lo; blk < hi; ++blk) s += histmat[blk * NBUCK + b];
    csum[c][b] = s;
    __syncthreads();
    if (t < NBUCK) {
        int r = 0;
        #pragma unroll
        for (int c2 = 0; c2 < 4; ++c2) { cbase[c2][t] = r; r += csum[c2][t]; }
        tot[t] = r;
    }
    __syncthreads();
    if (t == 0) {
        int r = 0;
        for (int b2 = 0; b2 < NBUCK; ++b2) { int v = tot[b2]; tot[b2] = r; r += v; }
        tot[NBUCK] = r;
    }
    __syncthreads();
    if (t <= NBUCK) bucketbase[t] = tot[t];
    int r = cbase[c][b];
    #pragma unroll 8
    for (int blk = lo; blk < hi; ++blk) {
        blockoff[blk * NBUCK + b] = r;
        r += histmat[blk * NBUCK + b];
    }
}

__global__ __launch_bounds__(256) void k_reorder(const int* __restrict__ src,
                                                 const int* __restrict__ dst,
                                                 const int* __restrict__ blockoff,
                                                 const int* __restrict__ bucketbase,
                                                 int2* __restrict__ esort) {
    __shared__ int lcur[NBUCK];
    int t = threadIdx.x;
    if (t < NBUCK) lcur[t] = 0;
    __syncthreads();
    int base = blockIdx.x * 2048;
    for (int i = t; i < 2048; i += 256) {
        int e = base + i;
        if (e < N_EDGES) {
            int d = dst[e];
            int b = d >> BSHIFT;
            int r = atomicAdd(&lcur[b], 1);
            esort[bucketbase[b] + blockoff[blockIdx.x * NBUCK + b] + r] =
                make_int2(src[e], d);
        }
    }
}

__global__ __launch_bounds__(256) void k_csr(const int2* __restrict__ esort,
                                             const int* __restrict__ bucketbase,
                                             int* __restrict__ rowptr,
                                             int* __restrict__ colidx,
                                             float* __restrict__ dinv) {
    __shared__ int lh[1 << BSHIFT];
    __shared__ int ctot[256];
    int t = threadIdx.x;
    int b = blockIdx.x;
    int node0 = b << BSHIFT;
    int nNodes = min(1 << BSHIFT, N_NODES - node0);
    int e0 = bucketbase[b], e1 = bucketbase[b + 1];
    #pragma unroll
    for (int i = t; i < (1 << BSHIFT); i += 256) lh[i] = 0;
    __syncthreads();
    for (int e = e0 + t; e < e1; e += 256)
        atomicAdd(&lh[esort[e].y - node0], 1);
    __syncthreads();
    int c0 = t * 8;
    int cnt[8];
    int s = 0;
    #pragma unroll
    for (int j = 0; j < 8; ++j) { cnt[j] = lh[c0 + j]; s += cnt[j]; }
    ctot[t] = s;
    __syncthreads();
    int v = ctot[t];
    for (int off = 1; off < 256; off <<= 1) {
        int x = (t >= off) ? ctot[t - off] : 0;
        __syncthreads();
        ctot[t] += x;
        __syncthreads();
    }
    int run = ctot[t] - v;
    #pragma unroll
    for (int j = 0; j < 8; ++j) {
        int idx = c0 + j;
        int cv = cnt[j];
        lh[idx] = run;
        if (idx < nNodes) {
            rowptr[node0 + idx] = e0 + run;
            dinv[node0 + idx]   = rsqrtf((float)cv + 1.f);
        }
        run += cv;
    }
    __syncthreads();
    for (int e = e0 + t; e < e1; e += 256) {
        int2 ed = esort[e];
        int r = atomicAdd(&lh[ed.y - node0], 1);
        colidx[e0 + r] = ed.x;
    }
    if (b == 0 && t == 0) rowptr[N_NODES] = N_EDGES;
}

// ---------------------------------------------------------------------------
// Fused gather + conv finalize. One wave per dst node, 8 edge-slots x 8
// col-lanes x bf16x8. R10: v_pk_add_f32 accumulation (3 ops/2 values vs 4),
// LDS slot-reduce (replaces 24 shfl + 24 add), all-64-lane epilogue
// (1 col/lane vs 48-op tail on 8 lanes). bf16 gather was issue-bound at
// 1.24 TB/s vs fp32's 2.4 TB/s (R4/R9 comparison), not fabric-bound.
// ---------------------------------------------------------------------------
template <int IN_MODE, bool RELU>
__global__ __launch_bounds__(256) void k_gather(const int* __restrict__ rowptr,
                                                const int* __restrict__ colidx,
                                                const unsigned short* __restrict__ HWb,
                                                const unsigned short* __restrict__ Hin,
                                                const float* __restrict__ dinv,
                                                const float* __restrict__ bias,
                                                const float* __restrict__ scsh,
                                                unsigned short* __restrict__ Out) {
    __shared__ float red[4][8][64];      // [wave][slot][col]
    const int wv   = threadIdx.x >> 6;
    const int d    = blockIdx.x * 4 + wv;           // grid exact: d < N_NODES
    const int lane = threadIdx.x & 63;
    const int slot = lane >> 3;          // 0..7 edge slot
    const int c8   = (lane & 7) << 3;    // column base (8 cols per lane)
    const int j0 = rowptr[d], j1 = rowptr[d + 1];

    f32x2 a0 = {0.f, 0.f}, a1 = {0.f, 0.f}, a2 = {0.f, 0.f}, a3 = {0.f, 0.f};

    if (slot == 7) {  // self-loop term
        uint4 v = *reinterpret_cast<const uint4*>(&HWb[(size_t)d * HID + c8]);
        a0 = pk_add(a0, bfpair(v.x));
        a1 = pk_add(a1, bfpair(v.y));
        a2 = pk_add(a2, bfpair(v.z));
        a3 = pk_add(a3, bfpair(v.w));
    }
    for (int j = j0 + slot; j < j1; j += 8) {
        int s = colidx[j];
        uint4 v = *reinterpret_cast<const uint4*>(&HWb[(size_t)s * HID + c8]);
        a0 = pk_add(a0, bfpair(v.x));
        a1 = pk_add(a1, bfpair(v.y));
        a2 = pk_add(a2, bfpair(v.z));
        a3 = pk_add(a3, bfpair(v.w));
    }

    // slot partials -> LDS (2-way bank aliasing = free), then 1 col per lane
    *reinterpret_cast<float4*>(&red[wv][slot][c8])     = make_float4(a0.x, a0.y, a1.x, a1.y);
    *reinterpret_cast<float4*>(&red[wv][slot][c8 + 4]) = make_float4(a2.x, a2.y, a3.x, a3.y);
    __syncthreads();

    const int col = lane;
    float s = 0.f;
    #pragma unroll
    for (int t2 = 0; t2 < 8; ++t2) s += red[wv][t2][col];

    float h = bflo((unsigned int)Hin[(size_t)d * HID + col]);
    if (IN_MODE == 1) h = h * scsh[col] + scsh[64 + col];
    float o = s * dinv[d] + bias[col] + h;
    if (RELU) o = fmaxf(o, 0.f);
    Out[(size_t)d * HID + col] = f2bf(o);
}

// ---------------------------------------------------------------------------
// Two-stage segment-mean pool over sorted batch (stage 2 fused into k_final)
// ---------------------------------------------------------------------------
__device__ __forceinline__ int lowerb(const int* __restrict__ b, int n, int v) {
    int lo = 0, hi = n;
    while (lo < hi) { int m = (lo + hi) >> 1; if (b[m] < v) lo = m + 1; else hi = m; }
    return lo;
}

__global__ __launch_bounds__(256) void k_pool1(const unsigned short* __restrict__ Y,
                                               const int* __restrict__ batch,
                                               float* __restrict__ partial2) {
    int g  = blockIdx.x >> 4;
    int sb = blockIdx.x & 15;
    int tid = threadIdx.x, col = tid & 63, rg = tid >> 6;
    int lo = lowerb(batch, N_NODES, g);
    int hi = lowerb(batch, N_NODES, g + 1);
    int cnt = hi - lo;
    int st = lo + (int)(((long long)cnt * sb) >> 4);
    int en = lo + (int)(((long long)cnt * (sb + 1)) >> 4);
    float s = 0.f;
    for (int r = st + rg; r < en; r += 4)
        s += bflo((unsigned int)Y[(size_t)r * HID + col]);
    __shared__ float ls[4][64];
    ls[rg][col] = s;
    __syncthreads();
    if (tid < 64)
        partial2[(size_t)blockIdx.x * 64 + tid] =
            ls[0][tid] + ls[1][tid] + ls[2][tid] + ls[3][tid];
}

// ---------------------------------------------------------------------------
// Final head (pool stage-2 + final BN fused; segment bounds hoisted to LDS)
// ---------------------------------------------------------------------------
__global__ __launch_bounds__(256) void k_final(const float* __restrict__ partial2,
                                               const int* __restrict__ batch,
                                               const float* __restrict__ scsh,
                                               const float* __restrict__ W0,
                                               const float* __restrict__ b0,
                                               const float* __restrict__ W1,
                                               const float* __restrict__ b1,
                                               const float* __restrict__ W2,
                                               const float* __restrict__ b2,
                                               float* __restrict__ out) {
    __shared__ float P[64][65];
    __shared__ float Z[64][65];
    __shared__ int sOff[NGRAPH + 1];
    int tid = threadIdx.x;
    if (tid <= NGRAPH) sOff[tid] = lowerb(batch, N_NODES, tid);
    __syncthreads();
    for (int i = tid; i < NGRAPH * HID; i += 256) {
        int g = i >> 6, c = i & 63;
        float S = 0.f;
        #pragma unroll
        for (int sb = 0; sb < POOL_SUB; ++sb)
            S += partial2[(size_t)(g * POOL_SUB + sb) * 64 + c];
        int cnt = sOff[g + 1] - sOff[g];
        float v = 0.f;
        if (cnt > 0) v = (S / (float)cnt) * scsh[c] + scsh[64 + c];
        P[g][c] = v;
    }
    __syncthreads();
    for (int t = 0; t < 16; ++t) {
        int o = tid + 256 * t; int r = o >> 6, c = o & 63;
        float acc = b0[c];
        #pragma unroll 8
        for (int k = 0; k < 64; ++k) acc += P[r][k] * W0[k * 64 + c];
        Z[r][c] = fmaxf(acc, 0.f);
    }
    __syncthreads();
    for (int t = 0; t < 16; ++t) {
        int o = tid + 256 * t; int r = o >> 6, c = o & 63;
        float acc = b1[c];
        #pragma unroll 8
        for (int k = 0; k < 64; ++k) acc += Z[r][k] * W1[k * 64 + c];
        P[r][c] = fmaxf(acc, 0.f);
    }
    __syncthreads();
    if (tid < NGRAPH * OUTC) {
        int r = tid >> 1, c = tid & 1;
        float acc = b2[c];
        #pragma unroll 8
        for (int k = 0; k < 64; ++k) acc += P[r][k] * W2[k * OUTC + c];
        out[tid] = acc;
    }
}

// ---------------------------------------------------------------------------
extern "C" void kernel_launch(void* const* d_in, const int* in_sizes, int n_in,
                              void* d_out, int out_size, void* d_ws, size_t ws_size,
                              hipStream_t stream) {
    const float* x        = (const float*)d_in[0];
    const int*   ei       = (const int*)d_in[1];
    const int*   batch    = (const int*)d_in[2];
    const float* pre_W    = (const float*)d_in[3];
    const float* pre_b    = (const float*)d_in[4];
    const float* pre_g    = (const float*)d_in[5];
    const float* pre_beta = (const float*)d_in[6];
    const float* conv_W   = (const float*)d_in[7];
    const float* conv_b   = (const float*)d_in[8];
    const float* post_W   = (const float*)d_in[9];
    const float* post_b   = (const float*)d_in[10];
    const float* post_g   = (const float*)d_in[11];
    const float* post_beta= (const float*)d_in[12];
    const float* fW0 = (const float*)d_in[13];
    const float* fb0 = (const float*)d_in[14];
    const float* fW1 = (const float*)d_in[15];
    const float* fb1 = (const float*)d_in[16];
    const float* fW2 = (const float*)d_in[17];
    const float* fb2 = (const float*)d_in[18];
    float* out = (float*)d_out;

    const size_t NH = (size_t)N_NODES * HID;
    unsigned short* Ab = (unsigned short*)d_ws;       // NH bf16
    unsigned short* Bb = Ab + NH;                     // NH bf16 (HW)
    unsigned short* Cb = Bb + NH;                     // NH bf16
    float* dinv     = (float*)(Cb + NH);              // N
    float* partial  = dinv + N_NODES;                 // GEMM_BLK*128
    float* scsh     = partial + (size_t)GEMM_BLK*128; // 6 slots of 128
    float* partial2 = scsh + 6 * 128;                 // 1024*64
    int* histmat    = (int*)(partial2 + NGRAPH * POOL_SUB * 64); // NEB_BLK*NBUCK
    int* blockoff   = histmat + NEB_BLK * NBUCK;      // NEB_BLK*NBUCK
    int* bucketbase = blockoff + NEB_BLK * NBUCK;     // NBUCK+1
    int* rowptr     = bucketbase + NBUCK + 1;         // N+1
    int* colidx     = rowptr + N_NODES + 1;           // E
    size_t eoff = (size_t)(colidx + N_EDGES - (int*)d_ws);
    eoff = (eoff + 1) & ~(size_t)1;
    int2* esort     = (int2*)((int*)d_ws + eoff);     // E int2

    const int* srcp = ei;
    const int* dstp = ei + N_EDGES;
    const int gNode4 = (N_NODES + 3) / 4;

    // ---- bucket-sorted CSR build (no global atomics) ----
    k_hist<<<NEB_BLK, 256, 0, stream>>>(dstp, histmat);
    k_escan<<<1, 256, 0, stream>>>(histmat, blockoff, bucketbase);
    k_reorder<<<NEB_BLK, 256, 0, stream>>>(srcp, dstp, blockoff, bucketbase, esort);
    k_csr<<<NBUCK_ACT, 256, 0, stream>>>(esort, bucketbase, rowptr, colidx, dinv);

    // ---- pre-processing: GEMM(+fused prev BN/ReLU, +stats) ----
    k_gemm<0, true,  true, false, true><<<GEMM_BLK, 256, 0, stream>>>(x, pre_W, pre_b, nullptr, nullptr, Ab, partial, N_NODES);
    k_statsfin<<<64, 256, 0, stream>>>(partial, pre_g, pre_beta, scsh + 0 * 128, N_NODES);

    k_gemm<2, false, true, false, true><<<GEMM_BLK, 256, 0, stream>>>(Ab, pre_W + 4096, pre_b + 64, nullptr, scsh + 0 * 128, Cb, partial, N_NODES);
    k_statsfin<<<64, 256, 0, stream>>>(partial, pre_g + 64, pre_beta + 64, scsh + 1 * 128, N_NODES);

    k_gemm<2, false, true, false, true><<<GEMM_BLK, 256, 0, stream>>>(Cb, pre_W + 2 * 4096, pre_b + 128, nullptr, scsh + 1 * 128, Ab, partial, N_NODES);
    k_statsfin<<<64, 256, 0, stream>>>(partial, pre_g + 128, pre_beta + 128, scsh + 2 * 128, N_NODES);

    // ---- GCNConv stack (all buffers bf16) ----
    for (int i = 0; i < 6; ++i) {
        const unsigned short* in = (i & 1) ? Cb : Ab;
        unsigned short*     outb = (i & 1) ? Ab : Cb;
        const float* Wl = conv_W + i * 4096;
        const float* bl = conv_b + i * 64;
        if (i == 0)
            k_gemm<1, false, false, true, false><<<GEMM_BLK, 256, 0, stream>>>(in, Wl, nullptr, dinv, scsh + 2 * 128, Bb, nullptr, N_NODES);
        else
            k_gemm<0, false, false, true, false><<<GEMM_BLK, 256, 0, stream>>>(in, Wl, nullptr, dinv, nullptr, Bb, nullptr, N_NODES);

        if (i == 0)
            k_gather<1, true ><<<gNode4, 256, 0, stream>>>(rowptr, colidx, Bb, in, dinv, bl, scsh + 2 * 128, outb);
        else if (i != 5)
            k_gather<0, true ><<<gNode4, 256, 0, stream>>>(rowptr, colidx, Bb, in, dinv, bl, nullptr, outb);
        else
            k_gather<0, false><<<gNode4, 256, 0, stream>>>(rowptr, colidx, Bb, in, dinv, bl, nullptr, outb);
    }
    // conv output in Ab

    // ---- post-processing ----
    k_gemm<0, false, true, false, true><<<GEMM_BLK, 256, 0, stream>>>(Ab, post_W, post_b, nullptr, nullptr, Cb, partial, N_NODES);
    k_statsfin<<<64, 256, 0, stream>>>(partial, post_g, post_beta, scsh + 3 * 128, N_NODES);

    k_gemm<2, false, true, false, true><<<GEMM_BLK, 256, 0, stream>>>(Cb, post_W + 4096, post_b + 64, nullptr, scsh + 3 * 128, Ab, partial, N_NODES);
    k_statsfin<<<64, 256, 0, stream>>>(partial, post_g + 64, post_beta + 64, scsh + 4 * 128, N_NODES);

    k_gemm<2, false, true, false, true><<<GEMM_BLK, 256, 0, stream>>>(Ab, post_W + 2 * 4096, post_b + 128, nullptr, scsh + 4 * 128, Cb, partial, N_NODES);
    k_statsfin<<<64, 256, 0, stream>>>(partial, post_g + 128, post_beta + 128, scsh + 5 * 128, N_NODES);

    // ---- pool stage 1 + fused(pool2 + BN + head) ----
    k_pool1<<<NGRAPH * POOL_SUB, 256, 0, stream>>>(Cb, batch, partial2);
    k_final<<<1, 256, 0, stream>>>(partial2, batch, scsh + 5 * 128,
                                   fW0, fb0, fW1, fb1, fW2, fb2, out);
}

// Round 11
// 479.486 us; speedup vs baseline: 1.3608x; 1.0425x over previous
//
#include <hip/hip_runtime.h>

#define N_NODES 100000
#define N_EDGES 800000
#define HID 64
#define NGRAPH 64
#define OUTC 2
#define BN_EPS 1e-5f
#define GEMM_BLK ((N_NODES + 63) / 64)      // 1563
#define POOL_SUB 16
// bucket-sorted CSR build
#define BSHIFT 11
#define NBUCK 64
#define NBUCK_ACT ((N_NODES + (1 << BSHIFT) - 1) >> BSHIFT)   // 49
#define NEB_BLK ((N_EDGES + 2047) / 2048)                      // 391

typedef __attribute__((ext_vector_type(8))) short bf16x8;
typedef __attribute__((ext_vector_type(4))) float f32x4;
typedef __attribute__((ext_vector_type(2))) float f32x2;

__device__ __forceinline__ unsigned short f2bf(float f) {
    unsigned int u = __float_as_uint(f);
    u = (u + 0x7FFFu + ((u >> 16) & 1u)) >> 16;   // round-to-nearest-even
    return (unsigned short)u;
}
__device__ __forceinline__ float bflo(unsigned int u) { return __uint_as_float(u << 16); }
__device__ __forceinline__ float bfhi(unsigned int u) { return __uint_as_float(u & 0xFFFF0000u); }
__device__ __forceinline__ unsigned int bfpack(float a, float b) {
    return (unsigned int)f2bf(a) | ((unsigned int)f2bf(b) << 16);
}
__device__ __forceinline__ f32x2 bfpair(unsigned int w) {
    f32x2 p;
    p.x = __uint_as_float(w << 16);
    p.y = __uint_as_float(w & 0xFFFF0000u);
    return p;
}
__device__ __forceinline__ f32x2 pk_add(f32x2 a, f32x2 b) {
    f32x2 d;
    asm("v_pk_add_f32 %0, %1, %2" : "=v"(d) : "v"(a), "v"(b));
    return d;
}

// ---------------------------------------------------------------------------
// GEMM via bf16 MFMA (unchanged from R10)
// ---------------------------------------------------------------------------
template <int IN_MODE, bool IN_FP32, bool ADD_BIAS, bool ROW_SCALE, bool STATS>
__global__ __launch_bounds__(256) void k_gemm(const void* __restrict__ Xv,
                                              const float* __restrict__ W,
                                              const float* __restrict__ bias,
                                              const float* __restrict__ dinv,
                                              const float* __restrict__ scsh,
                                              unsigned short* __restrict__ Y,
                                              float* __restrict__ partial, int n) {
    __shared__ __align__(16) unsigned short sXb[64][72];
    __shared__ __align__(16) unsigned short sWT[64][72];
    __shared__ float sDinv[64];
    const int tid  = threadIdx.x;
    const int row0 = blockIdx.x * 64;

    #pragma unroll
    for (int i = tid; i < 1024; i += 256) {
        int k = i >> 4, c4 = (i & 15) << 2;
        float4 w = *reinterpret_cast<const float4*>(&W[k * 64 + c4]);
        sWT[c4 + 0][k] = f2bf(w.x);
        sWT[c4 + 1][k] = f2bf(w.y);
        sWT[c4 + 2][k] = f2bf(w.z);
        sWT[c4 + 3][k] = f2bf(w.w);
    }
    if (IN_FP32) {
        const float* X = (const float*)Xv;
        #pragma unroll
        for (int f = tid; f < 1024; f += 256) {
            int r = f >> 4, c4 = (f & 15) << 2;
            float4 v = make_float4(0.f, 0.f, 0.f, 0.f);
            if (row0 + r < n)
                v = *reinterpret_cast<const float4*>(&X[(size_t)(row0 + r) * HID + c4]);
            if (IN_MODE >= 1) {
                float4 sc = *reinterpret_cast<const float4*>(&scsh[c4]);
                float4 sh = *reinterpret_cast<const float4*>(&scsh[64 + c4]);
                v.x = v.x * sc.x + sh.x; v.y = v.y * sc.y + sh.y;
                v.z = v.z * sc.z + sh.z; v.w = v.w * sc.w + sh.w;
                if (IN_MODE == 2) {
                    v.x = fmaxf(v.x, 0.f); v.y = fmaxf(v.y, 0.f);
                    v.z = fmaxf(v.z, 0.f); v.w = fmaxf(v.w, 0.f);
                }
            }
            sXb[r][c4 + 0] = f2bf(v.x);
            sXb[r][c4 + 1] = f2bf(v.y);
            sXb[r][c4 + 2] = f2bf(v.z);
            sXb[r][c4 + 3] = f2bf(v.w);
        }
    } else {
        const unsigned short* X = (const unsigned short*)Xv;
        #pragma unroll
        for (int f = tid; f < 512; f += 256) {
            int r = f >> 3, c8 = (f & 7) << 3;
            uint4 u = make_uint4(0u, 0u, 0u, 0u);
            if (row0 + r < n)
                u = *reinterpret_cast<const uint4*>(&X[(size_t)(row0 + r) * HID + c8]);
            if (IN_MODE >= 1) {
                float v[8];
                v[0] = bflo(u.x); v[1] = bfhi(u.x);
                v[2] = bflo(u.y); v[3] = bfhi(u.y);
                v[4] = bflo(u.z); v[5] = bfhi(u.z);
                v[6] = bflo(u.w); v[7] = bfhi(u.w);
                #pragma unroll
                for (int k = 0; k < 8; ++k) {
                    v[k] = v[k] * scsh[c8 + k] + scsh[64 + c8 + k];
                    if (IN_MODE == 2) v[k] = fmaxf(v[k], 0.f);
                }
                u.x = bfpack(v[0], v[1]); u.y = bfpack(v[2], v[3]);
                u.z = bfpack(v[4], v[5]); u.w = bfpack(v[6], v[7]);
            }
            *reinterpret_cast<uint4*>(&sXb[r][c8]) = u;
        }
    }
    if (ROW_SCALE && tid < 64)
        sDinv[tid] = (row0 + tid < n) ? dinv[row0 + tid] : 0.f;
    __syncthreads();

    const int lane = tid & 63;
    const int wv   = tid >> 6;
    const int cl   = lane & 15;
    const int kg   = lane >> 4;
    const int col  = (wv << 4) + cl;

    const f32x4 zero = {0.f, 0.f, 0.f, 0.f};
    f32x4 acc[4];
    #pragma unroll
    for (int m = 0; m < 4; ++m) acc[m] = zero;

    #pragma unroll
    for (int k0 = 0; k0 < 64; k0 += 32) {
        bf16x8 bfrag = *reinterpret_cast<const bf16x8*>(&sWT[col][k0 + (kg << 3)]);
        #pragma unroll
        for (int m = 0; m < 4; ++m) {
            bf16x8 afrag = *reinterpret_cast<const bf16x8*>(&sXb[(m << 4) + cl][k0 + (kg << 3)]);
            acc[m] = __builtin_amdgcn_mfma_f32_16x16x32_bf16(afrag, bfrag, acc[m], 0, 0, 0);
        }
    }

    const float bb = ADD_BIAS ? bias[col] : 0.f;
    float colS = 0.f, colQ = 0.f;
    #pragma unroll
    for (int m = 0; m < 4; ++m) {
        #pragma unroll
        for (int j = 0; j < 4; ++j) {
            int rl = (m << 4) + (kg << 2) + j;
            int r  = row0 + rl;
            if (r < n) {
                float s = ROW_SCALE ? sDinv[rl] : 1.f;
                float o = acc[m][j] * s + bb;
                Y[(size_t)r * HID + col] = f2bf(o);
                if (STATS) { colS += o; colQ += o * o; }
            }
        }
    }
    if (STATS) {
        colS += __shfl_xor(colS, 16); colQ += __shfl_xor(colQ, 16);
        colS += __shfl_xor(colS, 32); colQ += __shfl_xor(colQ, 32);
        if (kg == 0) {
            partial[blockIdx.x * 128 + col]      = colS;
            partial[blockIdx.x * 128 + 64 + col] = colQ;
        }
    }
}

// Reduce per-block partials -> scale/shift. One block per column.
__global__ __launch_bounds__(256) void k_statsfin(const float* __restrict__ partial,
                                                  const float* __restrict__ g,
                                                  const float* __restrict__ beta,
                                                  float* __restrict__ scsh, int n) {
    int c = blockIdx.x, t = threadIdx.x;
    float S = 0.f, Q = 0.f;
    for (int b = t; b < GEMM_BLK; b += 256) {
        S += partial[b * 128 + c];
        Q += partial[b * 128 + 64 + c];
    }
    __shared__ float ss[256], sq[256];
    ss[t] = S; sq[t] = Q;
    __syncthreads();
    for (int off = 128; off > 0; off >>= 1) {
        if (t < off) { ss[t] += ss[t + off]; sq[t] += sq[t + off]; }
        __syncthreads();
    }
    if (t == 0) {
        float nf = (float)n;
        float m  = ss[0] / nf;
        float v  = sq[0] / nf - m * m;
        float sc = rsqrtf(v + BN_EPS) * g[c];
        scsh[c]      = sc;
        scsh[64 + c] = beta[c] - m * sc;
    }
}

// ---------------------------------------------------------------------------
// Bucket-sorted CSR build (unchanged from R9)
// ---------------------------------------------------------------------------
__global__ __launch_bounds__(256) void k_hist(const int* __restrict__ dst,
                                              int* __restrict__ histmat) {
    __shared__ int lh[NBUCK];
    int t = threadIdx.x;
    if (t < NBUCK) lh[t] = 0;
    __syncthreads();
    int base = blockIdx.x * 2048;
    for (int i = t; i < 2048; i += 256) {
        int e = base + i;
        if (e < N_EDGES) atomicAdd(&lh[dst[e] >> BSHIFT], 1);
    }
    __syncthreads();
    if (t < NBUCK) histmat[blockIdx.x * NBUCK + t] = lh[t];
}

__global__ __launch_bounds__(256) void k_escan(const int* __restrict__ histmat,
                                               int* __restrict__ blockoff,
                                               int* __restrict__ bucketbase) {
    __shared__ int csum[4][NBUCK];
    __shared__ int cbase[4][NBUCK];
    __shared__ int tot[NBUCK + 1];
    int t = threadIdx.x;
    int b = t & 63, c = t >> 6;
    const int CHUNK = (NEB_BLK + 3) / 4;          // 98
    int lo = c * CHUNK, hi = min(lo + CHUNK, NEB_BLK);
    int s = 0;
    #pragma unroll 8
    for (int blk = lo; blk < hi; ++blk) s += histmat[blk * NBUCK + b];
    csum[c][b] = s;
    __syncthreads();
    if (t < NBUCK) {
        int r = 0;
        #pragma unroll
        for (int c2 = 0; c2 < 4; ++c2) { cbase[c2][t] = r; r += csum[c2][t]; }
        tot[t] = r;
    }
    __syncthreads();
    if (t == 0) {
        int r = 0;
        for (int b2 = 0; b2 < NBUCK; ++b2) { int v = tot[b2]; tot[b2] = r; r += v; }
        tot[NBUCK] = r;
    }
    __syncthreads();
    if (t <= NBUCK) bucketbase[t] = tot[t];
    int r = cbase[c][b];
    #pragma unroll 8
    for (int blk = lo; blk < hi; ++blk) {
        blockoff[blk * NBUCK + b] = r;
        r += histmat[blk * NBUCK + b];
    }
}

__global__ __launch_bounds__(256) void k_reorder(const int* __restrict__ src,
                                                 const int* __restrict__ dst,
                                                 const int* __restrict__ blockoff,
                                                 const int* __restrict__ bucketbase,
                                                 int2* __restrict__ esort) {
    __shared__ int lcur[NBUCK];
    int t = threadIdx.x;
    if (t < NBUCK) lcur[t] = 0;
    __syncthreads();
    int base = blockIdx.x * 2048;
    for (int i = t; i < 2048; i += 256) {
        int e = base + i;
        if (e < N_EDGES) {
            int d = dst[e];
            int b = d >> BSHIFT;
            int r = atomicAdd(&lcur[b], 1);
            esort[bucketbase[b] + blockoff[blockIdx.x * NBUCK + b] + r] =
                make_int2(src[e], d);
        }
    }
}

__global__ __launch_bounds__(256) void k_csr(const int2* __restrict__ esort,
                                             const int* __restrict__ bucketbase,
                                             int* __restrict__ rowptr,
                                             int* __restrict__ colidx,
                                             float* __restrict__ dinv) {
    __shared__ int lh[1 << BSHIFT];
    __shared__ int ctot[256];
    int t = threadIdx.x;
    int b = blockIdx.x;
    int node0 = b << BSHIFT;
    int nNodes = min(1 << BSHIFT, N_NODES - node0);
    int e0 = bucketbase[b], e1 = bucketbase[b + 1];
    #pragma unroll
    for (int i = t; i < (1 << BSHIFT); i += 256) lh[i] = 0;
    __syncthreads();
    for (int e = e0 + t; e < e1; e += 256)
        atomicAdd(&lh[esort[e].y - node0], 1);
    __syncthreads();
    int c0 = t * 8;
    int cnt[8];
    int s = 0;
    #pragma unroll
    for (int j = 0; j < 8; ++j) { cnt[j] = lh[c0 + j]; s += cnt[j]; }
    ctot[t] = s;
    __syncthreads();
    int v = ctot[t];
    for (int off = 1; off < 256; off <<= 1) {
        int x = (t >= off) ? ctot[t - off] : 0;
        __syncthreads();
        ctot[t] += x;
        __syncthreads();
    }
    int run = ctot[t] - v;
    #pragma unroll
    for (int j = 0; j < 8; ++j) {
        int idx = c0 + j;
        int cv = cnt[j];
        lh[idx] = run;
        if (idx < nNodes) {
            rowptr[node0 + idx] = e0 + run;
            dinv[node0 + idx]   = rsqrtf((float)cv + 1.f);
        }
        run += cv;
    }
    __syncthreads();
    for (int e = e0 + t; e < e1; e += 256) {
        int2 ed = esort[e];
        int r = atomicAdd(&lh[ed.y - node0], 1);
        colidx[e0 + r] = ed.x;
    }
    if (b == 0 && t == 0) rowptr[N_NODES] = N_EDGES;
}

// ---------------------------------------------------------------------------
// Fused gather + conv finalize (unchanged from R10)
// ---------------------------------------------------------------------------
template <int IN_MODE, bool RELU>
__global__ __launch_bounds__(256) void k_gather(const int* __restrict__ rowptr,
                                                const int* __restrict__ colidx,
                                                const unsigned short* __restrict__ HWb,
                                                const unsigned short* __restrict__ Hin,
                                                const float* __restrict__ dinv,
                                                const float* __restrict__ bias,
                                                const float* __restrict__ scsh,
                                                unsigned short* __restrict__ Out) {
    __shared__ float red[4][8][64];      // [wave][slot][col]
    const int wv   = threadIdx.x >> 6;
    const int d    = blockIdx.x * 4 + wv;           // grid exact: d < N_NODES
    const int lane = threadIdx.x & 63;
    const int slot = lane >> 3;
    const int c8   = (lane & 7) << 3;
    const int j0 = rowptr[d], j1 = rowptr[d + 1];

    f32x2 a0 = {0.f, 0.f}, a1 = {0.f, 0.f}, a2 = {0.f, 0.f}, a3 = {0.f, 0.f};

    if (slot == 7) {
        uint4 v = *reinterpret_cast<const uint4*>(&HWb[(size_t)d * HID + c8]);
        a0 = pk_add(a0, bfpair(v.x));
        a1 = pk_add(a1, bfpair(v.y));
        a2 = pk_add(a2, bfpair(v.z));
        a3 = pk_add(a3, bfpair(v.w));
    }
    for (int j = j0 + slot; j < j1; j += 8) {
        int s = colidx[j];
        uint4 v = *reinterpret_cast<const uint4*>(&HWb[(size_t)s * HID + c8]);
        a0 = pk_add(a0, bfpair(v.x));
        a1 = pk_add(a1, bfpair(v.y));
        a2 = pk_add(a2, bfpair(v.z));
        a3 = pk_add(a3, bfpair(v.w));
    }

    *reinterpret_cast<float4*>(&red[wv][slot][c8])     = make_float4(a0.x, a0.y, a1.x, a1.y);
    *reinterpret_cast<float4*>(&red[wv][slot][c8 + 4]) = make_float4(a2.x, a2.y, a3.x, a3.y);
    __syncthreads();

    const int col = lane;
    float s = 0.f;
    #pragma unroll
    for (int t2 = 0; t2 < 8; ++t2) s += red[wv][t2][col];

    float h = bflo((unsigned int)Hin[(size_t)d * HID + col]);
    if (IN_MODE == 1) h = h * scsh[col] + scsh[64 + col];
    float o = s * dinv[d] + bias[col] + h;
    if (RELU) o = fmaxf(o, 0.f);
    Out[(size_t)d * HID + col] = f2bf(o);
}

// ---------------------------------------------------------------------------
// Two-stage segment-mean pool over sorted batch (stage 2 fused into k_final)
// ---------------------------------------------------------------------------
__device__ __forceinline__ int lowerb(const int* __restrict__ b, int n, int v) {
    int lo = 0, hi = n;
    while (lo < hi) { int m = (lo + hi) >> 1; if (b[m] < v) lo = m + 1; else hi = m; }
    return lo;
}

__global__ __launch_bounds__(256) void k_pool1(const unsigned short* __restrict__ Y,
                                               const int* __restrict__ batch,
                                               float* __restrict__ partial2) {
    int g  = blockIdx.x >> 4;
    int sb = blockIdx.x & 15;
    int tid = threadIdx.x, col = tid & 63, rg = tid >> 6;
    int lo = lowerb(batch, N_NODES, g);
    int hi = lowerb(batch, N_NODES, g + 1);
    int cnt = hi - lo;
    int st = lo + (int)(((long long)cnt * sb) >> 4);
    int en = lo + (int)(((long long)cnt * (sb + 1)) >> 4);
    float s = 0.f;
    for (int r = st + rg; r < en; r += 4)
        s += bflo((unsigned int)Y[(size_t)r * HID + col]);
    __shared__ float ls[4][64];
    ls[rg][col] = s;
    __syncthreads();
    if (tid < 64)
        partial2[(size_t)blockIdx.x * 64 + tid] =
            ls[0][tid] + ls[1][tid] + ls[2][tid] + ls[3][tid];
}

// ---------------------------------------------------------------------------
// Final head. R11: W0/W1 staged into LDS (R10 version issued 1024 global
// loads/thread from ONE block at 1 wave/SIMD -> pure latency, ~45us).
// All inner-loop traffic now LDS; round-2 micro-tile (tr/tc 4x4) pattern.
// ---------------------------------------------------------------------------
__global__ __launch_bounds__(256) void k_final(const float* __restrict__ partial2,
                                               const int* __restrict__ batch,
                                               const float* __restrict__ scsh,
                                               const float* __restrict__ W0,
                                               const float* __restrict__ b0,
                                               const float* __restrict__ W1,
                                               const float* __restrict__ b1,
                                               const float* __restrict__ W2,
                                               const float* __restrict__ b2,
                                               float* __restrict__ out) {
    __shared__ float sA[64][68];     // activations (16B-aligned rows)
    __shared__ float sC[64][68];
    __shared__ float sW[64][64];     // staged weight matrix
    __shared__ int sOff[NGRAPH + 1];
    const int tid = threadIdx.x;
    const int tr = tid >> 4, tc = tid & 15;

    if (tid <= NGRAPH) sOff[tid] = lowerb(batch, N_NODES, tid);
    {   // stage W0 (coalesced float4)
        const float4* w = reinterpret_cast<const float4*>(W0);
        float4* s = reinterpret_cast<float4*>(&sW[0][0]);
        #pragma unroll
        for (int i = tid; i < 1024; i += 256) s[i] = w[i];
    }
    __syncthreads();

    // pool stage-2 + final BN -> sA
    for (int i = tid; i < NGRAPH * HID; i += 256) {
        int g = i >> 6, c = i & 63;
        float S = 0.f;
        #pragma unroll
        for (int sb = 0; sb < POOL_SUB; ++sb)
            S += partial2[(size_t)(g * POOL_SUB + sb) * 64 + c];
        int cnt = sOff[g + 1] - sOff[g];
        float v = 0.f;
        if (cnt > 0) v = (S / (float)cnt) * scsh[c] + scsh[64 + c];
        sA[g][c] = v;
    }
    __syncthreads();

    // layer 1: sC = relu(sA @ sW + b0)
    {
        float4 acc[4];
        #pragma unroll
        for (int i = 0; i < 4; ++i) acc[i] = make_float4(0.f, 0.f, 0.f, 0.f);
        #pragma unroll 16
        for (int k = 0; k < 64; ++k) {
            const float4 bv = *reinterpret_cast<const float4*>(&sW[k][tc << 2]);
            float a[4];
            #pragma unroll
            for (int i = 0; i < 4; ++i) a[i] = sA[(tr << 2) + i][k];
            #pragma unroll
            for (int i = 0; i < 4; ++i) {
                acc[i].x += a[i] * bv.x; acc[i].y += a[i] * bv.y;
                acc[i].z += a[i] * bv.z; acc[i].w += a[i] * bv.w;
            }
        }
        float4 bb = *reinterpret_cast<const float4*>(&b0[tc << 2]);
        #pragma unroll
        for (int i = 0; i < 4; ++i) {
            float4 o;
            o.x = fmaxf(acc[i].x + bb.x, 0.f);
            o.y = fmaxf(acc[i].y + bb.y, 0.f);
            o.z = fmaxf(acc[i].z + bb.z, 0.f);
            o.w = fmaxf(acc[i].w + bb.w, 0.f);
            *reinterpret_cast<float4*>(&sC[(tr << 2) + i][tc << 2]) = o;
        }
    }
    __syncthreads();
    {   // stage W1 (sW free after barrier)
        const float4* w = reinterpret_cast<const float4*>(W1);
        float4* s = reinterpret_cast<float4*>(&sW[0][0]);
        #pragma unroll
        for (int i = tid; i < 1024; i += 256) s[i] = w[i];
    }
    __syncthreads();

    // layer 2: sA = relu(sC @ sW + b1)
    {
        float4 acc[4];
        #pragma unroll
        for (int i = 0; i < 4; ++i) acc[i] = make_float4(0.f, 0.f, 0.f, 0.f);
        #pragma unroll 16
        for (int k = 0; k < 64; ++k) {
            const float4 bv = *reinterpret_cast<const float4*>(&sW[k][tc << 2]);
            float a[4];
            #pragma unroll
            for (int i = 0; i < 4; ++i) a[i] = sC[(tr << 2) + i][k];
            #pragma unroll
            for (int i = 0; i < 4; ++i) {
                acc[i].x += a[i] * bv.x; acc[i].y += a[i] * bv.y;
                acc[i].z += a[i] * bv.z; acc[i].w += a[i] * bv.w;
            }
        }
        float4 bb = *reinterpret_cast<const float4*>(&b1[tc << 2]);
        #pragma unroll
        for (int i = 0; i < 4; ++i) {
            float4 o;
            o.x = fmaxf(acc[i].x + bb.x, 0.f);
            o.y = fmaxf(acc[i].y + bb.y, 0.f);
            o.z = fmaxf(acc[i].z + bb.z, 0.f);
            o.w = fmaxf(acc[i].w + bb.w, 0.f);
            *reinterpret_cast<float4*>(&sA[(tr << 2) + i][tc << 2]) = o;
        }
    }
    __syncthreads();

    // layer 3: out[64,2] = sA @ W2 + b2  (W2 is 64x2 = 512B, L2-hot)
    if (tid < NGRAPH * OUTC) {
        int r = tid >> 1, c = tid & 1;
        float acc = b2[c];
        #pragma unroll 8
        for (int k = 0; k < 64; ++k) acc += sA[r][k] * W2[k * OUTC + c];
        out[tid] = acc;
    }
}

// ---------------------------------------------------------------------------
extern "C" void kernel_launch(void* const* d_in, const int* in_sizes, int n_in,
                              void* d_out, int out_size, void* d_ws, size_t ws_size,
                              hipStream_t stream) {
    const float* x        = (const float*)d_in[0];
    const int*   ei       = (const int*)d_in[1];
    const int*   batch    = (const int*)d_in[2];
    const float* pre_W    = (const float*)d_in[3];
    const float* pre_b    = (const float*)d_in[4];
    const float* pre_g    = (const float*)d_in[5];
    const float* pre_beta = (const float*)d_in[6];
    const float* conv_W   = (const float*)d_in[7];
    const float* conv_b   = (const float*)d_in[8];
    const float* post_W   = (const float*)d_in[9];
    const float* post_b   = (const float*)d_in[10];
    const float* post_g   = (const float*)d_in[11];
    const float* post_beta= (const float*)d_in[12];
    const float* fW0 = (const float*)d_in[13];
    const float* fb0 = (const float*)d_in[14];
    const float* fW1 = (const float*)d_in[15];
    const float* fb1 = (const float*)d_in[16];
    const float* fW2 = (const float*)d_in[17];
    const float* fb2 = (const float*)d_in[18];
    float* out = (float*)d_out;

    const size_t NH = (size_t)N_NODES * HID;
    unsigned short* Ab = (unsigned short*)d_ws;       // NH bf16
    unsigned short* Bb = Ab + NH;                     // NH bf16 (HW)
    unsigned short* Cb = Bb + NH;                     // NH bf16
    float* dinv     = (float*)(Cb + NH);              // N
    float* partial  = dinv + N_NODES;                 // GEMM_BLK*128
    float* scsh     = partial + (size_t)GEMM_BLK*128; // 6 slots of 128
    float* partial2 = scsh + 6 * 128;                 // 1024*64
    int* histmat    = (int*)(partial2 + NGRAPH * POOL_SUB * 64); // NEB_BLK*NBUCK
    int* blockoff   = histmat + NEB_BLK * NBUCK;      // NEB_BLK*NBUCK
    int* bucketbase = blockoff + NEB_BLK * NBUCK;     // NBUCK+1
    int* rowptr     = bucketbase + NBUCK + 1;         // N+1
    int* colidx     = rowptr + N_NODES + 1;           // E
    size_t eoff = (size_t)(colidx + N_EDGES - (int*)d_ws);
    eoff = (eoff + 1) & ~(size_t)1;
    int2* esort     = (int2*)((int*)d_ws + eoff);     // E int2

    const int* srcp = ei;
    const int* dstp = ei + N_EDGES;
    const int gNode4 = (N_NODES + 3) / 4;

    // ---- bucket-sorted CSR build (no global atomics) ----
    k_hist<<<NEB_BLK, 256, 0, stream>>>(dstp, histmat);
    k_escan<<<1, 256, 0, stream>>>(histmat, blockoff, bucketbase);
    k_reorder<<<NEB_BLK, 256, 0, stream>>>(srcp, dstp, blockoff, bucketbase, esort);
    k_csr<<<NBUCK_ACT, 256, 0, stream>>>(esort, bucketbase, rowptr, colidx, dinv);

    // ---- pre-processing: GEMM(+fused prev BN/ReLU, +stats) ----
    k_gemm<0, true,  true, false, true><<<GEMM_BLK, 256, 0, stream>>>(x, pre_W, pre_b, nullptr, nullptr, Ab, partial, N_NODES);
    k_statsfin<<<64, 256, 0, stream>>>(partial, pre_g, pre_beta, scsh + 0 * 128, N_NODES);

    k_gemm<2, false, true, false, true><<<GEMM_BLK, 256, 0, stream>>>(Ab, pre_W + 4096, pre_b + 64, nullptr, scsh + 0 * 128, Cb, partial, N_NODES);
    k_statsfin<<<64, 256, 0, stream>>>(partial, pre_g + 64, pre_beta + 64, scsh + 1 * 128, N_NODES);

    k_gemm<2, false, true, false, true><<<GEMM_BLK, 256, 0, stream>>>(Cb, pre_W + 2 * 4096, pre_b + 128, nullptr, scsh + 1 * 128, Ab, partial, N_NODES);
    k_statsfin<<<64, 256, 0, stream>>>(partial, pre_g + 128, pre_beta + 128, scsh + 2 * 128, N_NODES);

    // ---- GCNConv stack (all buffers bf16) ----
    for (int i = 0; i < 6; ++i) {
        const unsigned short* in = (i & 1) ? Cb : Ab;
        unsigned short*     outb = (i & 1) ? Ab : Cb;
        const float* Wl = conv_W + i * 4096;
        const float* bl = conv_b + i * 64;
        if (i == 0)
            k_gemm<1, false, false, true, false><<<GEMM_BLK, 256, 0, stream>>>(in, Wl, nullptr, dinv, scsh + 2 * 128, Bb, nullptr, N_NODES);
        else
            k_gemm<0, false, false, true, false><<<GEMM_BLK, 256, 0, stream>>>(in, Wl, nullptr, dinv, nullptr, Bb, nullptr, N_NODES);

        if (i == 0)
            k_gather<1, true ><<<gNode4, 256, 0, stream>>>(rowptr, colidx, Bb, in, dinv, bl, scsh + 2 * 128, outb);
        else if (i != 5)
            k_gather<0, true ><<<gNode4, 256, 0, stream>>>(rowptr, colidx, Bb, in, dinv, bl, nullptr, outb);
        else
            k_gather<0, false><<<gNode4, 256, 0, stream>>>(rowptr, colidx, Bb, in, dinv, bl, nullptr, outb);
    }
    // conv output in Ab

    // ---- post-processing ----
    k_gemm<0, false, true, false, true><<<GEMM_BLK, 256, 0, stream>>>(Ab, post_W, post_b, nullptr, nullptr, Cb, partial, N_NODES);
    k_statsfin<<<64, 256, 0, stream>>>(partial, post_g, post_beta, scsh + 3 * 128, N_NODES);

    k_gemm<2, false, true, false, true><<<GEMM_BLK, 256, 0, stream>>>(Cb, post_W + 4096, post_b + 64, nullptr, scsh + 3 * 128, Ab, partial, N_NODES);
    k_statsfin<<<64, 256, 0, stream>>>(partial, post_g + 64, post_beta + 64, scsh + 4 * 128, N_NODES);

    k_gemm<2, false, true, false, true><<<GEMM_BLK, 256, 0, stream>>>(Ab, post_W + 2 * 4096, post_b + 128, nullptr, scsh + 4 * 128, Cb, partial, N_NODES);
    k_statsfin<<<64, 256, 0, stream>>>(partial, post_g + 128, post_beta + 128, scsh + 5 * 128, N_NODES);

    // ---- pool stage 1 + fused(pool2 + BN + head) ----
    k_pool1<<<NGRAPH * POOL_SUB, 256, 0, stream>>>(Cb, batch, partial2);
    k_final<<<1, 256, 0, stream>>>(partial2, batch, scsh + 5 * 128,
                                   fW0, fb0, fW1, fb1, fW2, fb2, out);
}